// Round 1
// baseline (1027.243 us; speedup 1.0000x reference)
//
#include <hip/hip_runtime.h>
#include <hip/hip_bf16.h>
#include <math.h>

#define IN_DIM 128
#define HID 256
#define OUT_DIM 40
#define EPS 1e-5f

// ---------------- graph preprocessing ----------------

__global__ void hist_k(const int* __restrict__ dst, int* __restrict__ deg, int E) {
    for (int e = blockIdx.x * blockDim.x + threadIdx.x; e < E; e += gridDim.x * blockDim.x)
        atomicAdd(&deg[dst[e]], 1);
}

__global__ void dinv_k(const int* __restrict__ deg, float* __restrict__ dinv, int N) {
    int v = blockIdx.x * 256 + threadIdx.x;
    if (v < N) dinv[v] = rsqrtf((float)(deg[v] + 1));   // +1 self-loop; always > 0
}

// exclusive scan of deg -> row_ptr, single block of 1024 threads
__global__ __launch_bounds__(1024) void scan_k(const int* __restrict__ deg,
                                               int* __restrict__ rp, int n) {
    __shared__ int part[1024];
    int t = threadIdx.x;
    int chunk = (n + 1023) / 1024;
    int beg = t * chunk;
    int end = min(n, beg + chunk);
    int s = 0;
    for (int i = beg; i < end; ++i) s += deg[i];
    part[t] = s;
    __syncthreads();
    for (int off = 1; off < 1024; off <<= 1) {
        int v = 0;
        if (t >= off) v = part[t - off];
        __syncthreads();
        if (t >= off) part[t] += v;
        __syncthreads();
    }
    int run = (t == 0) ? 0 : part[t - 1];
    for (int i = beg; i < end; ++i) { rp[i] = run; run += deg[i]; }
    if (t == 1023) rp[n] = part[1023];
}

__global__ void fill_k(const int* __restrict__ src, const int* __restrict__ dst,
                       const int* __restrict__ rp, int* __restrict__ cnt,
                       int* __restrict__ col, int E) {
    for (int e = blockIdx.x * blockDim.x + threadIdx.x; e < E; e += gridDim.x * blockDim.x) {
        int d = dst[e];
        int p = atomicAdd(&cnt[d], 1);
        col[rp[d] + p] = src[e];
    }
}

// ---------------- fp32 tiled GEMM: C[M,Nc] = A[M,K] @ B[K,Nc] ----------------
// BM=BN=64, BK=16, 256 threads, 4x4 per thread.

__global__ __launch_bounds__(256) void gemm_f32(const float* __restrict__ A,
                                                const float* __restrict__ B,
                                                float* __restrict__ C,
                                                int M, int Nc, int K) {
    __shared__ float As[16][68];  // [k][m], +4 pad -> conflict-free stores
    __shared__ float Bs[16][68];  // [k][n]
    int tid = threadIdx.x;
    int tx = tid & 15, ty = tid >> 4;
    int row0 = blockIdx.y * 64;
    int col0 = blockIdx.x * 64;
    float acc[4][4] = {};
    for (int k0 = 0; k0 < K; k0 += 16) {
#pragma unroll
        for (int i = 0; i < 4; ++i) {
            int idx = tid + i * 256;
            int am = idx >> 4, ak = idx & 15;
            int r = row0 + am;
            As[ak][am] = (r < M) ? A[(size_t)r * K + k0 + ak] : 0.f;
        }
#pragma unroll
        for (int i = 0; i < 4; ++i) {
            int idx = tid + i * 256;
            int bk = idx >> 6, bn = idx & 63;
            int c = col0 + bn;
            Bs[bk][bn] = (c < Nc) ? B[(size_t)(k0 + bk) * Nc + c] : 0.f;
        }
        __syncthreads();
#pragma unroll
        for (int k = 0; k < 16; ++k) {
            float4 a = *(const float4*)&As[k][ty * 4];
            float4 b = *(const float4*)&Bs[k][tx * 4];
            float av[4] = {a.x, a.y, a.z, a.w};
            float bv[4] = {b.x, b.y, b.z, b.w};
#pragma unroll
            for (int i = 0; i < 4; ++i)
#pragma unroll
                for (int j = 0; j < 4; ++j) acc[i][j] += av[i] * bv[j];
        }
        __syncthreads();
    }
#pragma unroll
    for (int i = 0; i < 4; ++i) {
        int r = row0 + ty * 4 + i;
        if (r >= M) continue;
#pragma unroll
        for (int j = 0; j < 4; ++j) {
            int c = col0 + tx * 4 + j;
            if (c < Nc) C[(size_t)r * Nc + c] = acc[i][j];
        }
    }
}

// ---------------- CSR gather aggregation ----------------
// out[v,t] = dinv[v] * ( sum_e m[col_e,t]*dinv[col_e] + m[v,t]*dinv[v] ) + bias[t]

__global__ __launch_bounds__(256) void agg_h(const float* __restrict__ m,
                                             const int* __restrict__ col,
                                             const int* __restrict__ rp,
                                             const float* __restrict__ dinv,
                                             const float* __restrict__ bias,
                                             float* __restrict__ out) {
    int v = blockIdx.x;
    int t = threadIdx.x;
    float dv = dinv[v];
    int beg = rp[v], end = rp[v + 1];
    float acc = m[(size_t)v * HID + t] * dv;   // self-loop
    for (int e = beg; e < end; ++e) {
        int s = col[e];
        float ds = dinv[s];
        acc += m[(size_t)s * HID + t] * ds;
    }
    out[(size_t)v * HID + t] = acc * dv + bias[t];
}

__global__ __launch_bounds__(64) void agg_o(const float* __restrict__ m,
                                            const int* __restrict__ col,
                                            const int* __restrict__ rp,
                                            const float* __restrict__ dinv,
                                            const float* __restrict__ bias,
                                            float* __restrict__ out) {
    int v = blockIdx.x;
    int t = threadIdx.x;
    float dv = dinv[v];
    int beg = rp[v], end = rp[v + 1];
    float acc = (t < OUT_DIM) ? m[(size_t)v * OUT_DIM + t] * dv : 0.f;
    for (int e = beg; e < end; ++e) {
        int s = col[e];
        float ds = dinv[s];
        if (t < OUT_DIM) acc += m[(size_t)s * OUT_DIM + t] * ds;
    }
    if (t < OUT_DIM) out[(size_t)v * OUT_DIM + t] = acc * dv + bias[t];
}

// ---------------- BatchNorm ----------------

__global__ __launch_bounds__(256) void bn_stats(const float* __restrict__ h,
                                                float* __restrict__ stats, int N) {
    int t = threadIdx.x;
    int r0 = blockIdx.x * 128;
    int rend = min(r0 + 128, N);
    float s = 0.f, ss = 0.f;
    for (int r = r0; r < rend; ++r) {
        float v = h[(size_t)r * HID + t];
        s += v;
        ss += v * v;
    }
    atomicAdd(&stats[t], s);
    atomicAdd(&stats[HID + t], ss);
}

__global__ void bn_finalize(float* __restrict__ stats, const float* __restrict__ g,
                            const float* __restrict__ be, int N) {
    int t = threadIdx.x;
    float mu = stats[t] / (float)N;
    float var = stats[HID + t] / (float)N - mu * mu;
    float sc = g[t] * rsqrtf(var + EPS);
    stats[2 * HID + t] = sc;
    stats[3 * HID + t] = be[t] - mu * sc;
}

__global__ __launch_bounds__(256) void bn_apply_relu(float* __restrict__ h,
                                                     const float* __restrict__ stats,
                                                     size_t n4) {
    const float* scale = stats + 2 * HID;
    const float* shift = stats + 3 * HID;
    for (size_t i = blockIdx.x * 256 + threadIdx.x; i < n4; i += (size_t)gridDim.x * 256) {
        float4 v = ((float4*)h)[i];
        int c = (int)(i & 63) * 4;
        v.x = fmaxf(v.x * scale[c + 0] + shift[c + 0], 0.f);
        v.y = fmaxf(v.y * scale[c + 1] + shift[c + 1], 0.f);
        v.z = fmaxf(v.z * scale[c + 2] + shift[c + 2], 0.f);
        v.w = fmaxf(v.w * scale[c + 3] + shift[c + 3], 0.f);
        ((float4*)h)[i] = v;
    }
}

// ---------------- head: h@Wl + bl, then log_softmax (4 nodes/block, 1 wave each) --------

__global__ __launch_bounds__(256) void head_k(const float* __restrict__ h,
                                              const float* __restrict__ Wl,
                                              const float* __restrict__ bl,
                                              float* __restrict__ out, int N) {
    __shared__ float sW[OUT_DIM * OUT_DIM];
    __shared__ float sb[OUT_DIM];
    __shared__ float sh[4][OUT_DIM];
    int tid = threadIdx.x;
    for (int i = tid; i < OUT_DIM * OUT_DIM; i += 256) sW[i] = Wl[i];
    if (tid < OUT_DIM) sb[tid] = bl[tid];
    int w = tid >> 6, lane = tid & 63;
    int v = blockIdx.x * 4 + w;
    if (v < N && lane < OUT_DIM) sh[w][lane] = h[(size_t)v * OUT_DIM + lane];
    __syncthreads();
    float o = -INFINITY;
    if (v < N && lane < OUT_DIM) {
        float acc = sb[lane];
#pragma unroll
        for (int k = 0; k < OUT_DIM; ++k) acc += sh[w][k] * sW[k * OUT_DIM + lane];
        o = acc;
    }
    float mx = o;
    for (int off = 32; off; off >>= 1) mx = fmaxf(mx, __shfl_xor(mx, off));
    float ex = (v < N && lane < OUT_DIM) ? expf(o - mx) : 0.f;
    float s = ex;
    for (int off = 32; off; off >>= 1) s += __shfl_xor(s, off);
    if (v < N && lane < OUT_DIM) out[(size_t)v * OUT_DIM + lane] = o - mx - logf(s);
}

// ---------------- launch ----------------

extern "C" void kernel_launch(void* const* d_in, const int* in_sizes, int n_in,
                              void* d_out, int out_size, void* d_ws, size_t ws_size,
                              hipStream_t stream) {
    const float* x   = (const float*)d_in[0];
    const int*  eidx = (const int*)d_in[1];
    const float* W1 = (const float*)d_in[2];
    const float* b1 = (const float*)d_in[3];
    const float* g1 = (const float*)d_in[4];
    const float* be1 = (const float*)d_in[5];
    const float* W2 = (const float*)d_in[6];
    const float* b2 = (const float*)d_in[7];
    const float* g2 = (const float*)d_in[8];
    const float* be2 = (const float*)d_in[9];
    const float* W3 = (const float*)d_in[10];
    const float* b3 = (const float*)d_in[11];
    const float* Wl = (const float*)d_in[12];
    const float* bl = (const float*)d_in[13];
    float* out = (float*)d_out;

    const int N = in_sizes[0] / IN_DIM;
    const int E = in_sizes[1] / 2;
    const int* src = eidx;
    const int* dst = eidx + E;

    // workspace carve-up
    size_t off = 0;
    char* ws = (char*)d_ws;
    auto carve = [&](size_t bytes) -> void* {
        void* p = ws + off;
        off += (bytes + 255) & ~(size_t)255;
        return p;
    };
    int*   degi = (int*)carve((size_t)N * 4);
    float* dinv = (float*)carve((size_t)N * 4);
    int*   rp   = (int*)carve((size_t)(N + 1) * 4);
    int*   cnt  = (int*)carve((size_t)N * 4);
    int*   col  = (int*)carve((size_t)E * 4);
    float* stats = (float*)carve((size_t)4 * HID * 4);
    float* mbuf = (float*)carve((size_t)N * HID * 4);
    float* hbuf = (float*)carve((size_t)N * HID * 4);

    // --- graph preprocessing ---
    hipMemsetAsync(degi, 0, (size_t)N * 4, stream);
    hist_k<<<1024, 256, 0, stream>>>(dst, degi, E);
    dinv_k<<<(N + 255) / 256, 256, 0, stream>>>(degi, dinv, N);
    scan_k<<<1, 1024, 0, stream>>>(degi, rp, N);
    hipMemsetAsync(cnt, 0, (size_t)N * 4, stream);
    fill_k<<<1024, 256, 0, stream>>>(src, dst, rp, cnt, col, E);

    dim3 gemm_grid_h((HID + 63) / 64, (N + 63) / 64);
    dim3 gemm_grid_o((OUT_DIM + 63) / 64, (N + 63) / 64);
    size_t n4 = (size_t)N * HID / 4;

    // --- layer 1 ---
    gemm_f32<<<gemm_grid_h, 256, 0, stream>>>(x, W1, mbuf, N, HID, IN_DIM);
    agg_h<<<N, 256, 0, stream>>>(mbuf, col, rp, dinv, b1, hbuf);
    hipMemsetAsync(stats, 0, (size_t)2 * HID * 4, stream);
    bn_stats<<<(N + 127) / 128, 256, 0, stream>>>(hbuf, stats, N);
    bn_finalize<<<1, HID, 0, stream>>>(stats, g1, be1, N);
    bn_apply_relu<<<4096, 256, 0, stream>>>(hbuf, stats, n4);

    // --- layer 2 ---
    gemm_f32<<<gemm_grid_h, 256, 0, stream>>>(hbuf, W2, mbuf, N, HID, HID);
    agg_h<<<N, 256, 0, stream>>>(mbuf, col, rp, dinv, b2, hbuf);
    hipMemsetAsync(stats, 0, (size_t)2 * HID * 4, stream);
    bn_stats<<<(N + 127) / 128, 256, 0, stream>>>(hbuf, stats, N);
    bn_finalize<<<1, HID, 0, stream>>>(stats, g2, be2, N);
    bn_apply_relu<<<4096, 256, 0, stream>>>(hbuf, stats, n4);

    // --- layer 3 (no BN/ReLU) ---
    gemm_f32<<<gemm_grid_o, 256, 0, stream>>>(hbuf, W3, mbuf, N, OUT_DIM, HID);
    agg_o<<<N, 64, 0, stream>>>(mbuf, col, rp, dinv, b3, hbuf);

    // --- head: linear + log_softmax ---
    head_k<<<(N + 3) / 4, 256, 0, stream>>>(hbuf, Wl, bl, out, N);
}

// Round 2
// 633.658 us; speedup vs baseline: 1.6211x; 1.6211x over previous
//
#include <hip/hip_runtime.h>
#include <hip/hip_bf16.h>
#include <math.h>

#define IN_DIM 128
#define HID 256
#define OUT_DIM 40
#define EPS 1e-5f

typedef __attribute__((ext_vector_type(8))) short short8;
typedef __attribute__((ext_vector_type(4))) float floatx4;

__device__ __forceinline__ float b2f(unsigned short u) {
    union { unsigned int i; float f; } c; c.i = ((unsigned int)u) << 16; return c.f;
}
__device__ __forceinline__ unsigned short f2b(float f) {
    union { float f; unsigned int i; } c; c.f = f;
    unsigned int r = c.i + 0x7FFF + ((c.i >> 16) & 1);
    return (unsigned short)(r >> 16);
}

// ---------------- graph preprocessing ----------------

__global__ void hist_k(const int* __restrict__ dst, int* __restrict__ deg, int E) {
    for (int e = blockIdx.x * blockDim.x + threadIdx.x; e < E; e += gridDim.x * blockDim.x)
        atomicAdd(&deg[dst[e]], 1);
}

__global__ void dinv_k(const int* __restrict__ deg, float* __restrict__ dinv, int N) {
    int v = blockIdx.x * 256 + threadIdx.x;
    if (v < N) dinv[v] = rsqrtf((float)(deg[v] + 1));   // +1 self-loop; always > 0
}

__global__ __launch_bounds__(1024) void scan_k(const int* __restrict__ deg,
                                               int* __restrict__ rp, int n) {
    __shared__ int part[1024];
    int t = threadIdx.x;
    int chunk = (n + 1023) / 1024;
    int beg = t * chunk;
    int end = min(n, beg + chunk);
    int s = 0;
    for (int i = beg; i < end; ++i) s += deg[i];
    part[t] = s;
    __syncthreads();
    for (int off = 1; off < 1024; off <<= 1) {
        int v = 0;
        if (t >= off) v = part[t - off];
        __syncthreads();
        if (t >= off) part[t] += v;
        __syncthreads();
    }
    int run = (t == 0) ? 0 : part[t - 1];
    for (int i = beg; i < end; ++i) { rp[i] = run; run += deg[i]; }
    if (t == 1023) rp[n] = part[1023];
}

__global__ void fill_k(const int* __restrict__ src, const int* __restrict__ dst,
                       const int* __restrict__ rp, int* __restrict__ cnt,
                       int* __restrict__ col, int E) {
    for (int e = blockIdx.x * blockDim.x + threadIdx.x; e < E; e += gridDim.x * blockDim.x) {
        int d = dst[e];
        int p = atomicAdd(&cnt[d], 1);
        col[rp[d] + p] = src[e];
    }
}

// ---------------- dtype conversion ----------------

__global__ void f2b_k(const float* __restrict__ in, unsigned short* __restrict__ out, size_t n) {
    for (size_t i = blockIdx.x * 256 + threadIdx.x; i < n; i += (size_t)gridDim.x * 256)
        out[i] = f2b(in[i]);
}

// W [K][Nc] fp32 -> Wt [NcPad][K] bf16, rows >= Nc zeroed
__global__ void wt_k(const float* __restrict__ W, unsigned short* __restrict__ Wt,
                     int K, int Nc, int NcPad) {
    int i = blockIdx.x * 256 + threadIdx.x;
    if (i >= NcPad * K) return;
    int n = i / K, k = i - n * K;
    Wt[i] = (n < Nc) ? f2b(W[(size_t)k * Nc + n]) : 0;
}

// ---------------- bf16 MFMA GEMM ----------------
// C[M][ldc](bf16) = (A[M][K](bf16) @ Bt^T) * dinv[row]
// Bt is [>=gridDim.x*128][K] bf16 (W transposed, K contiguous).
// Tile 128x128, 256 threads = 4 waves (2x2), each wave 64x64 = 4x4 MFMA 16x16x32 tiles.

__global__ __launch_bounds__(256) void gemm_bf16(const unsigned short* __restrict__ A,
                                                 const unsigned short* __restrict__ Bt,
                                                 unsigned short* __restrict__ C,
                                                 const float* __restrict__ dinv,
                                                 int M, int Nc, int K, int ldc) {
    __shared__ unsigned short As[128][40];  // 32 k + 8 pad -> 2-way conflicts only
    __shared__ unsigned short Bs[128][40];
    int tid = threadIdx.x;
    int wave = tid >> 6, lane = tid & 63;
    int wm = wave >> 1, wn = wave & 1;
    int quad = lane >> 4, r16 = lane & 15;
    int row0 = blockIdx.y * 128, col0 = blockIdx.x * 128;

    floatx4 acc[4][4] = {};

    for (int k0 = 0; k0 < K; k0 += 32) {
#pragma unroll
        for (int i = 0; i < 2; ++i) {
            int idx = tid * 2 + i;          // 512 chunks of 8 elems
            int r = idx >> 2;               // 0..127
            int ko = (idx & 3) * 8;
            int ar = min(row0 + r, M - 1);
            *(uint4*)&As[r][ko] = *(const uint4*)&A[(size_t)ar * K + k0 + ko];
            *(uint4*)&Bs[r][ko] = *(const uint4*)&Bt[(size_t)(col0 + r) * K + k0 + ko];
        }
        __syncthreads();
        short8 a[4], b[4];
#pragma unroll
        for (int mt = 0; mt < 4; ++mt)
            a[mt] = *(const short8*)&As[wm * 64 + mt * 16 + r16][quad * 8];
#pragma unroll
        for (int nt = 0; nt < 4; ++nt)
            b[nt] = *(const short8*)&Bs[wn * 64 + nt * 16 + r16][quad * 8];
#pragma unroll
        for (int mt = 0; mt < 4; ++mt)
#pragma unroll
            for (int nt = 0; nt < 4; ++nt)
                acc[mt][nt] = __builtin_amdgcn_mfma_f32_16x16x32_bf16(a[mt], b[nt], acc[mt][nt], 0, 0, 0);
        __syncthreads();
    }

#pragma unroll
    for (int mt = 0; mt < 4; ++mt) {
#pragma unroll
        for (int r = 0; r < 4; ++r) {
            int row = row0 + wm * 64 + mt * 16 + quad * 4 + r;
            if (row >= M) continue;
            float dv = dinv[row];
#pragma unroll
            for (int nt = 0; nt < 4; ++nt) {
                int colg = col0 + wn * 64 + nt * 16 + r16;
                if (colg < Nc)
                    C[(size_t)row * ldc + colg] = f2b(acc[mt][nt][r] * dv);
            }
        }
    }
}

// ---------------- CSR gather aggregation (bf16 rows, pre-scaled by dinv[src]) --------
// out[v,:] = bf16( dinv[v] * ( sum_e m'[col_e,:] + m'[v,:] ) + bias )

__global__ __launch_bounds__(256) void agg_h(const unsigned short* __restrict__ m,
                                             const int* __restrict__ col,
                                             const int* __restrict__ rp,
                                             const float* __restrict__ dinv,
                                             const float* __restrict__ bias,
                                             unsigned short* __restrict__ out,
                                             int N) {
    int v = blockIdx.x * 4 + (threadIdx.x >> 6);
    if (v >= N) return;
    int lane = threadIdx.x & 63;
    int c0 = lane * 4;
    float dv = dinv[v];
    int beg = rp[v], end = rp[v + 1];
    float a0, a1, a2, a3;
    {
        ushort4 r = *(const ushort4*)&m[(size_t)v * HID + c0];
        a0 = b2f(r.x); a1 = b2f(r.y); a2 = b2f(r.z); a3 = b2f(r.w);
    }
    int e = beg;
    for (; e + 4 <= end; e += 4) {
        int s0 = col[e], s1 = col[e + 1], s2 = col[e + 2], s3 = col[e + 3];
        ushort4 r0 = *(const ushort4*)&m[(size_t)s0 * HID + c0];
        ushort4 r1 = *(const ushort4*)&m[(size_t)s1 * HID + c0];
        ushort4 r2 = *(const ushort4*)&m[(size_t)s2 * HID + c0];
        ushort4 r3 = *(const ushort4*)&m[(size_t)s3 * HID + c0];
        a0 += (b2f(r0.x) + b2f(r1.x)) + (b2f(r2.x) + b2f(r3.x));
        a1 += (b2f(r0.y) + b2f(r1.y)) + (b2f(r2.y) + b2f(r3.y));
        a2 += (b2f(r0.z) + b2f(r1.z)) + (b2f(r2.z) + b2f(r3.z));
        a3 += (b2f(r0.w) + b2f(r1.w)) + (b2f(r2.w) + b2f(r3.w));
    }
    for (; e < end; ++e) {
        int s = col[e];
        ushort4 r = *(const ushort4*)&m[(size_t)s * HID + c0];
        a0 += b2f(r.x); a1 += b2f(r.y); a2 += b2f(r.z); a3 += b2f(r.w);
    }
    ushort4 o;
    o.x = f2b(a0 * dv + bias[c0 + 0]);
    o.y = f2b(a1 * dv + bias[c0 + 1]);
    o.z = f2b(a2 * dv + bias[c0 + 2]);
    o.w = f2b(a3 * dv + bias[c0 + 3]);
    *(ushort4*)&out[(size_t)v * HID + c0] = o;
}

// layer-3 version: 40 cols bf16 in, fp32 out
__global__ __launch_bounds__(256) void agg_o(const unsigned short* __restrict__ m,
                                             const int* __restrict__ col,
                                             const int* __restrict__ rp,
                                             const float* __restrict__ dinv,
                                             const float* __restrict__ bias,
                                             float* __restrict__ out,
                                             int N) {
    int v = blockIdx.x * 4 + (threadIdx.x >> 6);
    if (v >= N) return;
    int lane = threadIdx.x & 63;
    if (lane >= 20) return;
    int c0 = lane * 2;
    float dv = dinv[v];
    int beg = rp[v], end = rp[v + 1];
    float a0, a1;
    {
        ushort2 r = *(const ushort2*)&m[(size_t)v * OUT_DIM + c0];
        a0 = b2f(r.x); a1 = b2f(r.y);
    }
    int e = beg;
    for (; e + 4 <= end; e += 4) {
        int s0 = col[e], s1 = col[e + 1], s2 = col[e + 2], s3 = col[e + 3];
        ushort2 r0 = *(const ushort2*)&m[(size_t)s0 * OUT_DIM + c0];
        ushort2 r1 = *(const ushort2*)&m[(size_t)s1 * OUT_DIM + c0];
        ushort2 r2 = *(const ushort2*)&m[(size_t)s2 * OUT_DIM + c0];
        ushort2 r3 = *(const ushort2*)&m[(size_t)s3 * OUT_DIM + c0];
        a0 += (b2f(r0.x) + b2f(r1.x)) + (b2f(r2.x) + b2f(r3.x));
        a1 += (b2f(r0.y) + b2f(r1.y)) + (b2f(r2.y) + b2f(r3.y));
    }
    for (; e < end; ++e) {
        int s = col[e];
        ushort2 r = *(const ushort2*)&m[(size_t)s * OUT_DIM + c0];
        a0 += b2f(r.x); a1 += b2f(r.y);
    }
    out[(size_t)v * OUT_DIM + c0 + 0] = a0 * dv + bias[c0 + 0];
    out[(size_t)v * OUT_DIM + c0 + 1] = a1 * dv + bias[c0 + 1];
}

// ---------------- BatchNorm (bf16 h) ----------------

__global__ __launch_bounds__(256) void bn_stats(const unsigned short* __restrict__ h,
                                                float* __restrict__ stats, int N) {
    int t = threadIdx.x;
    int r0 = blockIdx.x * 128;
    int rend = min(r0 + 128, N);
    float s = 0.f, ss = 0.f;
    for (int r = r0; r < rend; ++r) {
        float v = b2f(h[(size_t)r * HID + t]);
        s += v;
        ss += v * v;
    }
    atomicAdd(&stats[t], s);
    atomicAdd(&stats[HID + t], ss);
}

__global__ void bn_finalize(float* __restrict__ stats, const float* __restrict__ g,
                            const float* __restrict__ be, int N) {
    int t = threadIdx.x;
    float mu = stats[t] / (float)N;
    float var = stats[HID + t] / (float)N - mu * mu;
    float sc = g[t] * rsqrtf(var + EPS);
    stats[2 * HID + t] = sc;
    stats[3 * HID + t] = be[t] - mu * sc;
}

__global__ __launch_bounds__(256) void bn_apply_relu(unsigned short* __restrict__ h,
                                                     const float* __restrict__ stats,
                                                     size_t n4) {
    const float* scale = stats + 2 * HID;
    const float* shift = stats + 3 * HID;
    unsigned long long* h2 = (unsigned long long*)h;   // 4 bf16 per elem
    for (size_t i = blockIdx.x * 256 + threadIdx.x; i < n4; i += (size_t)gridDim.x * 256) {
        unsigned long long u = h2[i];
        int c = (int)(i & 63) * 4;
        unsigned short e0 = (unsigned short)u, e1 = (unsigned short)(u >> 16),
                       e2 = (unsigned short)(u >> 32), e3 = (unsigned short)(u >> 48);
        float f0 = fmaxf(b2f(e0) * scale[c + 0] + shift[c + 0], 0.f);
        float f1 = fmaxf(b2f(e1) * scale[c + 1] + shift[c + 1], 0.f);
        float f2 = fmaxf(b2f(e2) * scale[c + 2] + shift[c + 2], 0.f);
        float f3 = fmaxf(b2f(e3) * scale[c + 3] + shift[c + 3], 0.f);
        h2[i] = (unsigned long long)f2b(f0) | ((unsigned long long)f2b(f1) << 16) |
                ((unsigned long long)f2b(f2) << 32) | ((unsigned long long)f2b(f3) << 48);
    }
}

// ---------------- head: h@Wl + bl, then log_softmax ----------------

__global__ __launch_bounds__(256) void head_k(const float* __restrict__ h,
                                              const float* __restrict__ Wl,
                                              const float* __restrict__ bl,
                                              float* __restrict__ out, int N) {
    __shared__ float sW[OUT_DIM * OUT_DIM];
    __shared__ float sb[OUT_DIM];
    __shared__ float sh[4][OUT_DIM];
    int tid = threadIdx.x;
    for (int i = tid; i < OUT_DIM * OUT_DIM; i += 256) sW[i] = Wl[i];
    if (tid < OUT_DIM) sb[tid] = bl[tid];
    int w = tid >> 6, lane = tid & 63;
    int v = blockIdx.x * 4 + w;
    if (v < N && lane < OUT_DIM) sh[w][lane] = h[(size_t)v * OUT_DIM + lane];
    __syncthreads();
    float o = -INFINITY;
    if (v < N && lane < OUT_DIM) {
        float acc = sb[lane];
#pragma unroll
        for (int k = 0; k < OUT_DIM; ++k) acc += sh[w][k] * sW[k * OUT_DIM + lane];
        o = acc;
    }
    float mx = o;
    for (int off = 32; off; off >>= 1) mx = fmaxf(mx, __shfl_xor(mx, off));
    float ex = (v < N && lane < OUT_DIM) ? expf(o - mx) : 0.f;
    float s = ex;
    for (int off = 32; off; off >>= 1) s += __shfl_xor(s, off);
    if (v < N && lane < OUT_DIM) out[(size_t)v * OUT_DIM + lane] = o - mx - logf(s);
}

// ---------------- launch ----------------

extern "C" void kernel_launch(void* const* d_in, const int* in_sizes, int n_in,
                              void* d_out, int out_size, void* d_ws, size_t ws_size,
                              hipStream_t stream) {
    const float* x   = (const float*)d_in[0];
    const int*  eidx = (const int*)d_in[1];
    const float* W1 = (const float*)d_in[2];
    const float* b1 = (const float*)d_in[3];
    const float* g1 = (const float*)d_in[4];
    const float* be1 = (const float*)d_in[5];
    const float* W2 = (const float*)d_in[6];
    const float* b2 = (const float*)d_in[7];
    const float* g2 = (const float*)d_in[8];
    const float* be2 = (const float*)d_in[9];
    const float* W3 = (const float*)d_in[10];
    const float* b3 = (const float*)d_in[11];
    const float* Wl = (const float*)d_in[12];
    const float* bl = (const float*)d_in[13];
    float* out = (float*)d_out;

    const int N = in_sizes[0] / IN_DIM;
    const int E = in_sizes[1] / 2;
    const int* src = eidx;
    const int* dst = eidx + E;

    size_t off = 0;
    char* ws = (char*)d_ws;
    auto carve = [&](size_t bytes) -> void* {
        void* p = ws + off;
        off += (bytes + 255) & ~(size_t)255;
        return p;
    };
    int*   degi = (int*)carve((size_t)N * 4);
    float* dinv = (float*)carve((size_t)N * 4);
    int*   rp   = (int*)carve((size_t)(N + 1) * 4);
    int*   cnt  = (int*)carve((size_t)N * 4);
    int*   col  = (int*)carve((size_t)E * 4);
    float* stats = (float*)carve((size_t)4 * HID * 4);
    unsigned short* xb  = (unsigned short*)carve((size_t)N * IN_DIM * 2);
    unsigned short* W1t = (unsigned short*)carve((size_t)256 * IN_DIM * 2);
    unsigned short* W2t = (unsigned short*)carve((size_t)256 * HID * 2);
    unsigned short* W3t = (unsigned short*)carve((size_t)128 * HID * 2);
    unsigned short* mbuf = (unsigned short*)carve((size_t)N * HID * 2);
    unsigned short* hbuf = (unsigned short*)carve((size_t)N * HID * 2);
    float* hout = (float*)carve((size_t)N * OUT_DIM * 4);

    // --- graph preprocessing ---
    hipMemsetAsync(degi, 0, (size_t)N * 4, stream);
    hist_k<<<1024, 256, 0, stream>>>(dst, degi, E);
    dinv_k<<<(N + 255) / 256, 256, 0, stream>>>(degi, dinv, N);
    scan_k<<<1, 1024, 0, stream>>>(degi, rp, N);
    hipMemsetAsync(cnt, 0, (size_t)N * 4, stream);
    fill_k<<<1024, 256, 0, stream>>>(src, dst, rp, cnt, col, E);

    // --- dtype conversion ---
    f2b_k<<<4096, 256, 0, stream>>>(x, xb, (size_t)N * IN_DIM);
    wt_k<<<(256 * IN_DIM + 255) / 256, 256, 0, stream>>>(W1, W1t, IN_DIM, 256, 256);
    wt_k<<<(256 * HID + 255) / 256, 256, 0, stream>>>(W2, W2t, HID, 256, 256);
    wt_k<<<(128 * HID + 255) / 256, 256, 0, stream>>>(W3, W3t, HID, OUT_DIM, 128);

    int mblocks = (N + 127) / 128;
    dim3 gg1(2, mblocks), gg3(1, mblocks);
    int aggblocks = (N + 3) / 4;
    size_t n4 = (size_t)N * HID / 4;

    // --- layer 1 ---
    gemm_bf16<<<gg1, 256, 0, stream>>>(xb, W1t, mbuf, dinv, N, HID, IN_DIM, HID);
    agg_h<<<aggblocks, 256, 0, stream>>>(mbuf, col, rp, dinv, b1, hbuf, N);
    hipMemsetAsync(stats, 0, (size_t)2 * HID * 4, stream);
    bn_stats<<<(N + 127) / 128, 256, 0, stream>>>(hbuf, stats, N);
    bn_finalize<<<1, HID, 0, stream>>>(stats, g1, be1, N);
    bn_apply_relu<<<2048, 256, 0, stream>>>(hbuf, stats, n4);

    // --- layer 2 ---
    gemm_bf16<<<gg1, 256, 0, stream>>>(hbuf, W2t, mbuf, dinv, N, HID, HID, HID);
    agg_h<<<aggblocks, 256, 0, stream>>>(mbuf, col, rp, dinv, b2, hbuf, N);
    hipMemsetAsync(stats, 0, (size_t)2 * HID * 4, stream);
    bn_stats<<<(N + 127) / 128, 256, 0, stream>>>(hbuf, stats, N);
    bn_finalize<<<1, HID, 0, stream>>>(stats, g2, be2, N);
    bn_apply_relu<<<2048, 256, 0, stream>>>(hbuf, stats, n4);

    // --- layer 3 ---
    gemm_bf16<<<gg3, 256, 0, stream>>>(hbuf, W3t, mbuf, dinv, N, OUT_DIM, HID, OUT_DIM);
    agg_o<<<aggblocks, 256, 0, stream>>>(mbuf, col, rp, dinv, b3, hout, N);

    // --- head ---
    head_k<<<aggblocks, 256, 0, stream>>>(hout, Wl, bl, out, N);
}

// Round 3
// 542.516 us; speedup vs baseline: 1.8935x; 1.1680x over previous
//
#include <hip/hip_runtime.h>
#include <hip/hip_bf16.h>
#include <math.h>

#define IN_DIM 128
#define HID 256
#define OUT_DIM 40
#define EPS 1e-5f

typedef __attribute__((ext_vector_type(8))) short short8;
typedef __attribute__((ext_vector_type(4))) float floatx4;

__device__ __forceinline__ float b2f(unsigned short u) {
    union { unsigned int i; float f; } c; c.i = ((unsigned int)u) << 16; return c.f;
}
__device__ __forceinline__ unsigned short f2b(float f) {
    union { float f; unsigned int i; } c; c.f = f;
    unsigned int r = c.i + 0x7FFF + ((c.i >> 16) & 1);
    return (unsigned short)(r >> 16);
}

// ---------------- graph preprocessing ----------------

__global__ void hist_k(const int* __restrict__ dst, int* __restrict__ deg, int E) {
    for (int e = blockIdx.x * blockDim.x + threadIdx.x; e < E; e += gridDim.x * blockDim.x)
        atomicAdd(&deg[dst[e]], 1);
}

__global__ void dinv_k(const int* __restrict__ deg, float* __restrict__ dinv, int N) {
    int v = blockIdx.x * 256 + threadIdx.x;
    if (v < N) dinv[v] = rsqrtf((float)(deg[v] + 1));   // +1 self-loop; always > 0
}

// --- 3-phase exclusive scan of deg -> rp (N <= 256*256) ---

__global__ __launch_bounds__(256) void scan_a(const int* __restrict__ deg,
                                              int* __restrict__ bsum, int n) {
    __shared__ int red[256];
    int t = threadIdx.x;
    int i = blockIdx.x * 256 + t;
    red[t] = (i < n) ? deg[i] : 0;
    __syncthreads();
    for (int off = 128; off; off >>= 1) {
        if (t < off) red[t] += red[t + off];
        __syncthreads();
    }
    if (t == 0) bsum[blockIdx.x] = red[0];
}

__global__ __launch_bounds__(256) void scan_b(const int* __restrict__ bsum,
                                              int* __restrict__ boff, int nb) {
    __shared__ int s[256];
    int t = threadIdx.x;
    s[t] = (t < nb) ? bsum[t] : 0;
    __syncthreads();
    for (int off = 1; off < 256; off <<= 1) {
        int v = 0;
        if (t >= off) v = s[t - off];
        __syncthreads();
        if (t >= off) s[t] += v;
        __syncthreads();
    }
    boff[t] = (t == 0) ? 0 : s[t - 1];   // exclusive
}

__global__ __launch_bounds__(256) void scan_c(const int* __restrict__ deg,
                                              const int* __restrict__ boff,
                                              int* __restrict__ rp, int n) {
    __shared__ int s[256];
    int t = threadIdx.x;
    int i = blockIdx.x * 256 + t;
    int d = (i < n) ? deg[i] : 0;
    s[t] = d;
    __syncthreads();
    for (int off = 1; off < 256; off <<= 1) {
        int v = 0;
        if (t >= off) v = s[t - off];
        __syncthreads();
        if (t >= off) s[t] += v;
        __syncthreads();
    }
    int base = boff[blockIdx.x];
    if (i < n) rp[i] = base + s[t] - d;
    if (i == n - 1) rp[n] = base + s[t];
}

__global__ void fill_k(const int* __restrict__ src, const int* __restrict__ dst,
                       const int* __restrict__ rp, int* __restrict__ cnt,
                       int* __restrict__ col, int E) {
    for (int e = blockIdx.x * blockDim.x + threadIdx.x; e < E; e += gridDim.x * blockDim.x) {
        int d = dst[e];
        int p = atomicAdd(&cnt[d], 1);
        col[rp[d] + p] = src[e];
    }
}

// ---------------- dtype conversion ----------------

// x -> bf16, pre-scaled by dinv[row]  (row = i >> 7 since IN_DIM=128)
__global__ void f2bs_k(const float* __restrict__ in, const float* __restrict__ dinv,
                       unsigned short* __restrict__ out, size_t n) {
    for (size_t i = blockIdx.x * 256 + threadIdx.x; i < n; i += (size_t)gridDim.x * 256)
        out[i] = f2b(in[i] * dinv[i >> 7]);
}

// W [K][Nc] fp32 -> Wt [NcPad][K] bf16, rows >= Nc zeroed
__global__ void wt_k(const float* __restrict__ W, unsigned short* __restrict__ Wt,
                     int K, int Nc, int NcPad) {
    int i = blockIdx.x * 256 + threadIdx.x;
    if (i >= NcPad * K) return;
    int n = i / K, k = i - n * K;
    Wt[i] = (n < Nc) ? f2b(W[(size_t)k * Nc + n]) : 0;
}

// ---------------- bf16 MFMA GEMM ----------------
// C[M][ldc](bf16) = (A[M][K](bf16) @ Bt^T) * rowscale[row] + bias[col]
// Bt is [>=gridDim.x*128][K] bf16 (W transposed, K contiguous).
// Tile 128x128, 256 threads = 4 waves (2x2), each wave 64x64 = 4x4 MFMA 16x16x32 tiles.

__global__ __launch_bounds__(256) void gemm_bf16(const unsigned short* __restrict__ A,
                                                 const unsigned short* __restrict__ Bt,
                                                 unsigned short* __restrict__ C,
                                                 const float* __restrict__ rowscale,
                                                 const float* __restrict__ bias,
                                                 int M, int Nc, int K, int ldc) {
    __shared__ unsigned short As[128][40];  // 32 k + 8 pad -> 2-way conflicts only
    __shared__ unsigned short Bs[128][40];
    int tid = threadIdx.x;
    int wave = tid >> 6, lane = tid & 63;
    int wm = wave >> 1, wn = wave & 1;
    int quad = lane >> 4, r16 = lane & 15;
    int row0 = blockIdx.y * 128, col0 = blockIdx.x * 128;

    floatx4 acc[4][4] = {};

    for (int k0 = 0; k0 < K; k0 += 32) {
#pragma unroll
        for (int i = 0; i < 2; ++i) {
            int idx = tid * 2 + i;          // 512 chunks of 8 elems
            int r = idx >> 2;               // 0..127
            int ko = (idx & 3) * 8;
            int ar = min(row0 + r, M - 1);
            *(uint4*)&As[r][ko] = *(const uint4*)&A[(size_t)ar * K + k0 + ko];
            *(uint4*)&Bs[r][ko] = *(const uint4*)&Bt[(size_t)(col0 + r) * K + k0 + ko];
        }
        __syncthreads();
        short8 a[4], b[4];
#pragma unroll
        for (int mt = 0; mt < 4; ++mt)
            a[mt] = *(const short8*)&As[wm * 64 + mt * 16 + r16][quad * 8];
#pragma unroll
        for (int nt = 0; nt < 4; ++nt)
            b[nt] = *(const short8*)&Bs[wn * 64 + nt * 16 + r16][quad * 8];
#pragma unroll
        for (int mt = 0; mt < 4; ++mt)
#pragma unroll
            for (int nt = 0; nt < 4; ++nt)
                acc[mt][nt] = __builtin_amdgcn_mfma_f32_16x16x32_bf16(a[mt], b[nt], acc[mt][nt], 0, 0, 0);
        __syncthreads();
    }

#pragma unroll
    for (int mt = 0; mt < 4; ++mt) {
#pragma unroll
        for (int r = 0; r < 4; ++r) {
            int row = row0 + wm * 64 + mt * 16 + quad * 4 + r;
            if (row >= M) continue;
            float dv = rowscale ? rowscale[row] : 1.f;
#pragma unroll
            for (int nt = 0; nt < 4; ++nt) {
                int colg = col0 + wn * 64 + nt * 16 + r16;
                if (colg < Nc) {
                    float v = acc[mt][nt][r] * dv + (bias ? bias[colg] : 0.f);
                    C[(size_t)row * ldc + colg] = f2b(v);
                }
            }
        }
    }
}

// ---------------- CSR gather aggregation (bf16 rows, pre-scaled by dinv[src]) --------

// 128-col version (aggregates x before the layer-1 GEMM). out = bf16(dv * sum)
__global__ __launch_bounds__(256) void agg_x(const unsigned short* __restrict__ m,
                                             const int* __restrict__ col,
                                             const int* __restrict__ rp,
                                             const float* __restrict__ dinv,
                                             unsigned short* __restrict__ out,
                                             int N) {
    int v = blockIdx.x * 4 + (threadIdx.x >> 6);
    if (v >= N) return;
    int lane = threadIdx.x & 63;
    int c0 = lane * 2;
    float dv = dinv[v];
    int beg = rp[v], end = rp[v + 1];
    float a0, a1;
    {
        ushort2 r = *(const ushort2*)&m[(size_t)v * IN_DIM + c0];
        a0 = b2f(r.x); a1 = b2f(r.y);
    }
    int e = beg;
    for (; e + 8 <= end; e += 8) {
        ushort2 rr[8];
#pragma unroll
        for (int j = 0; j < 8; ++j)
            rr[j] = *(const ushort2*)&m[(size_t)col[e + j] * IN_DIM + c0];
#pragma unroll
        for (int j = 0; j < 8; ++j) { a0 += b2f(rr[j].x); a1 += b2f(rr[j].y); }
    }
    for (; e < end; ++e) {
        ushort2 r = *(const ushort2*)&m[(size_t)col[e] * IN_DIM + c0];
        a0 += b2f(r.x); a1 += b2f(r.y);
    }
    ushort2 o;
    o.x = f2b(a0 * dv);
    o.y = f2b(a1 * dv);
    *(ushort2*)&out[(size_t)v * IN_DIM + c0] = o;
}

// 256-col version. out[v,:] = bf16( dv * ( sum_e m'[col_e,:] + m'[v,:] ) + bias )
__global__ __launch_bounds__(256) void agg_h(const unsigned short* __restrict__ m,
                                             const int* __restrict__ col,
                                             const int* __restrict__ rp,
                                             const float* __restrict__ dinv,
                                             const float* __restrict__ bias,
                                             unsigned short* __restrict__ out,
                                             int N) {
    int v = blockIdx.x * 4 + (threadIdx.x >> 6);
    if (v >= N) return;
    int lane = threadIdx.x & 63;
    int c0 = lane * 4;
    float dv = dinv[v];
    int beg = rp[v], end = rp[v + 1];
    float a0, a1, a2, a3;
    {
        ushort4 r = *(const ushort4*)&m[(size_t)v * HID + c0];
        a0 = b2f(r.x); a1 = b2f(r.y); a2 = b2f(r.z); a3 = b2f(r.w);
    }
    int e = beg;
    for (; e + 8 <= end; e += 8) {
        ushort4 rr[8];
#pragma unroll
        for (int j = 0; j < 8; ++j)
            rr[j] = *(const ushort4*)&m[(size_t)col[e + j] * HID + c0];
#pragma unroll
        for (int j = 0; j < 8; ++j) {
            a0 += b2f(rr[j].x); a1 += b2f(rr[j].y); a2 += b2f(rr[j].z); a3 += b2f(rr[j].w);
        }
    }
    for (; e < end; ++e) {
        ushort4 r = *(const ushort4*)&m[(size_t)col[e] * HID + c0];
        a0 += b2f(r.x); a1 += b2f(r.y); a2 += b2f(r.z); a3 += b2f(r.w);
    }
    ushort4 o;
    o.x = f2b(a0 * dv + bias[c0 + 0]);
    o.y = f2b(a1 * dv + bias[c0 + 1]);
    o.z = f2b(a2 * dv + bias[c0 + 2]);
    o.w = f2b(a3 * dv + bias[c0 + 3]);
    *(ushort4*)&out[(size_t)v * HID + c0] = o;
}

// layer-3 version: 40 cols bf16 in, fp32 out
__global__ __launch_bounds__(256) void agg_o(const unsigned short* __restrict__ m,
                                             const int* __restrict__ col,
                                             const int* __restrict__ rp,
                                             const float* __restrict__ dinv,
                                             const float* __restrict__ bias,
                                             float* __restrict__ out,
                                             int N) {
    int v = blockIdx.x * 4 + (threadIdx.x >> 6);
    if (v >= N) return;
    int lane = threadIdx.x & 63;
    if (lane >= 20) return;
    int c0 = lane * 2;
    float dv = dinv[v];
    int beg = rp[v], end = rp[v + 1];
    float a0, a1;
    {
        ushort2 r = *(const ushort2*)&m[(size_t)v * OUT_DIM + c0];
        a0 = b2f(r.x); a1 = b2f(r.y);
    }
    int e = beg;
    for (; e + 8 <= end; e += 8) {
        ushort2 rr[8];
#pragma unroll
        for (int j = 0; j < 8; ++j)
            rr[j] = *(const ushort2*)&m[(size_t)col[e + j] * OUT_DIM + c0];
#pragma unroll
        for (int j = 0; j < 8; ++j) { a0 += b2f(rr[j].x); a1 += b2f(rr[j].y); }
    }
    for (; e < end; ++e) {
        ushort2 r = *(const ushort2*)&m[(size_t)col[e] * OUT_DIM + c0];
        a0 += b2f(r.x); a1 += b2f(r.y);
    }
    out[(size_t)v * OUT_DIM + c0 + 0] = a0 * dv + bias[c0 + 0];
    out[(size_t)v * OUT_DIM + c0 + 1] = a1 * dv + bias[c0 + 1];
}

// ---------------- BatchNorm (bf16 h) ----------------

__global__ __launch_bounds__(256) void bn_stats(const unsigned short* __restrict__ h,
                                                float* __restrict__ stats, int N) {
    int t = threadIdx.x;
    int r0 = blockIdx.x * 128;
    int rend = min(r0 + 128, N);
    float s = 0.f, ss = 0.f;
    for (int r = r0; r < rend; ++r) {
        float v = b2f(h[(size_t)r * HID + t]);
        s += v;
        ss += v * v;
    }
    atomicAdd(&stats[t], s);
    atomicAdd(&stats[HID + t], ss);
}

__global__ void bn_finalize(float* __restrict__ stats, const float* __restrict__ g,
                            const float* __restrict__ be, int N) {
    int t = threadIdx.x;
    float mu = stats[t] / (float)N;
    float var = stats[HID + t] / (float)N - mu * mu;
    float sc = g[t] * rsqrtf(var + EPS);
    stats[2 * HID + t] = sc;
    stats[3 * HID + t] = be[t] - mu * sc;
}

__global__ __launch_bounds__(256) void bn_apply_relu(unsigned short* __restrict__ h,
                                                     const float* __restrict__ stats,
                                                     size_t n4) {
    const float* scale = stats + 2 * HID;
    const float* shift = stats + 3 * HID;
    unsigned long long* h2 = (unsigned long long*)h;   // 4 bf16 per elem
    for (size_t i = blockIdx.x * 256 + threadIdx.x; i < n4; i += (size_t)gridDim.x * 256) {
        unsigned long long u = h2[i];
        int c = (int)(i & 63) * 4;
        unsigned short e0 = (unsigned short)u, e1 = (unsigned short)(u >> 16),
                       e2 = (unsigned short)(u >> 32), e3 = (unsigned short)(u >> 48);
        float f0 = fmaxf(b2f(e0) * scale[c + 0] + shift[c + 0], 0.f);
        float f1 = fmaxf(b2f(e1) * scale[c + 1] + shift[c + 1], 0.f);
        float f2 = fmaxf(b2f(e2) * scale[c + 2] + shift[c + 2], 0.f);
        float f3 = fmaxf(b2f(e3) * scale[c + 3] + shift[c + 3], 0.f);
        h2[i] = (unsigned long long)f2b(f0) | ((unsigned long long)f2b(f1) << 16) |
                ((unsigned long long)f2b(f2) << 32) | ((unsigned long long)f2b(f3) << 48);
    }
}

// ---------------- head: h@Wl + bl, then log_softmax ----------------

__global__ __launch_bounds__(256) void head_k(const float* __restrict__ h,
                                              const float* __restrict__ Wl,
                                              const float* __restrict__ bl,
                                              float* __restrict__ out, int N) {
    __shared__ float sW[OUT_DIM * OUT_DIM];
    __shared__ float sb[OUT_DIM];
    __shared__ float sh[4][OUT_DIM];
    int tid = threadIdx.x;
    for (int i = tid; i < OUT_DIM * OUT_DIM; i += 256) sW[i] = Wl[i];
    if (tid < OUT_DIM) sb[tid] = bl[tid];
    int w = tid >> 6, lane = tid & 63;
    int v = blockIdx.x * 4 + w;
    if (v < N && lane < OUT_DIM) sh[w][lane] = h[(size_t)v * OUT_DIM + lane];
    __syncthreads();
    float o = -INFINITY;
    if (v < N && lane < OUT_DIM) {
        float acc = sb[lane];
#pragma unroll
        for (int k = 0; k < OUT_DIM; ++k) acc += sh[w][k] * sW[k * OUT_DIM + lane];
        o = acc;
    }
    float mx = o;
    for (int off = 32; off; off >>= 1) mx = fmaxf(mx, __shfl_xor(mx, off));
    float ex = (v < N && lane < OUT_DIM) ? expf(o - mx) : 0.f;
    float s = ex;
    for (int off = 32; off; off >>= 1) s += __shfl_xor(s, off);
    if (v < N && lane < OUT_DIM) out[(size_t)v * OUT_DIM + lane] = o - mx - logf(s);
}

// ---------------- launch ----------------

extern "C" void kernel_launch(void* const* d_in, const int* in_sizes, int n_in,
                              void* d_out, int out_size, void* d_ws, size_t ws_size,
                              hipStream_t stream) {
    const float* x   = (const float*)d_in[0];
    const int*  eidx = (const int*)d_in[1];
    const float* W1 = (const float*)d_in[2];
    const float* b1 = (const float*)d_in[3];
    const float* g1 = (const float*)d_in[4];
    const float* be1 = (const float*)d_in[5];
    const float* W2 = (const float*)d_in[6];
    const float* b2 = (const float*)d_in[7];
    const float* g2 = (const float*)d_in[8];
    const float* be2 = (const float*)d_in[9];
    const float* W3 = (const float*)d_in[10];
    const float* b3 = (const float*)d_in[11];
    const float* Wl = (const float*)d_in[12];
    const float* bl = (const float*)d_in[13];
    float* out = (float*)d_out;

    const int N = in_sizes[0] / IN_DIM;
    const int E = in_sizes[1] / 2;
    const int* src = eidx;
    const int* dst = eidx + E;
    const int nb = (N + 255) / 256;   // scan blocks, must be <= 256

    size_t off = 0;
    char* ws = (char*)d_ws;
    auto carve = [&](size_t bytes) -> void* {
        void* p = ws + off;
        off += (bytes + 255) & ~(size_t)255;
        return p;
    };
    int*   degi = (int*)carve((size_t)N * 4);
    float* dinv = (float*)carve((size_t)N * 4);
    int*   rp   = (int*)carve((size_t)(N + 1) * 4);
    int*   cnt  = (int*)carve((size_t)N * 4);
    int*   col  = (int*)carve((size_t)E * 4);
    int*   bsum = (int*)carve(256 * 4);
    int*   boff = (int*)carve(257 * 4);
    float* stats = (float*)carve((size_t)4 * HID * 4);
    unsigned short* xb  = (unsigned short*)carve((size_t)N * IN_DIM * 2);
    unsigned short* axb = (unsigned short*)carve((size_t)N * IN_DIM * 2);
    unsigned short* W1t = (unsigned short*)carve((size_t)256 * IN_DIM * 2);
    unsigned short* W2t = (unsigned short*)carve((size_t)256 * HID * 2);
    unsigned short* W3t = (unsigned short*)carve((size_t)128 * HID * 2);
    unsigned short* mbuf = (unsigned short*)carve((size_t)N * HID * 2);
    unsigned short* hbuf = (unsigned short*)carve((size_t)N * HID * 2);
    float* hout = (float*)carve((size_t)N * OUT_DIM * 4);

    // --- graph preprocessing ---
    hipMemsetAsync(degi, 0, (size_t)N * 4, stream);
    hist_k<<<1024, 256, 0, stream>>>(dst, degi, E);
    dinv_k<<<(N + 255) / 256, 256, 0, stream>>>(degi, dinv, N);
    scan_a<<<nb, 256, 0, stream>>>(degi, bsum, N);
    scan_b<<<1, 256, 0, stream>>>(bsum, boff, nb);
    scan_c<<<nb, 256, 0, stream>>>(degi, boff, rp, N);
    hipMemsetAsync(cnt, 0, (size_t)N * 4, stream);
    fill_k<<<1024, 256, 0, stream>>>(src, dst, rp, cnt, col, E);

    // --- dtype conversion ---
    f2bs_k<<<2048, 256, 0, stream>>>(x, dinv, xb, (size_t)N * IN_DIM);
    wt_k<<<(256 * IN_DIM + 255) / 256, 256, 0, stream>>>(W1, W1t, IN_DIM, 256, 256);
    wt_k<<<(256 * HID + 255) / 256, 256, 0, stream>>>(W2, W2t, HID, 256, 256);
    wt_k<<<(128 * HID + 255) / 256, 256, 0, stream>>>(W3, W3t, HID, OUT_DIM, 128);

    int mblocks = (N + 127) / 128;
    dim3 gg1(2, mblocks), gg3(1, mblocks);
    int aggblocks = (N + 3) / 4;
    size_t n4 = (size_t)N * HID / 4;

    // --- layer 1: aggregate x (128 cols), then GEMM with +b1 epilogue ---
    agg_x<<<aggblocks, 256, 0, stream>>>(xb, col, rp, dinv, axb, N);
    gemm_bf16<<<gg1, 256, 0, stream>>>(axb, W1t, hbuf, nullptr, b1, N, HID, IN_DIM, HID);
    hipMemsetAsync(stats, 0, (size_t)2 * HID * 4, stream);
    bn_stats<<<(N + 127) / 128, 256, 0, stream>>>(hbuf, stats, N);
    bn_finalize<<<1, HID, 0, stream>>>(stats, g1, be1, N);
    bn_apply_relu<<<2048, 256, 0, stream>>>(hbuf, stats, n4);

    // --- layer 2 ---
    gemm_bf16<<<gg1, 256, 0, stream>>>(hbuf, W2t, mbuf, dinv, nullptr, N, HID, HID, HID);
    agg_h<<<aggblocks, 256, 0, stream>>>(mbuf, col, rp, dinv, b2, hbuf, N);
    hipMemsetAsync(stats, 0, (size_t)2 * HID * 4, stream);
    bn_stats<<<(N + 127) / 128, 256, 0, stream>>>(hbuf, stats, N);
    bn_finalize<<<1, HID, 0, stream>>>(stats, g2, be2, N);
    bn_apply_relu<<<2048, 256, 0, stream>>>(hbuf, stats, n4);

    // --- layer 3 ---
    gemm_bf16<<<gg3, 256, 0, stream>>>(hbuf, W3t, mbuf, dinv, nullptr, N, OUT_DIM, HID, OUT_DIM);
    agg_o<<<aggblocks, 256, 0, stream>>>(mbuf, col, rp, dinv, b3, hout, N);

    // --- head ---
    head_k<<<aggblocks, 256, 0, stream>>>(hout, Wl, bl, out, N);
}

// Round 4
// 496.896 us; speedup vs baseline: 2.0673x; 1.0918x over previous
//
#include <hip/hip_runtime.h>
#include <hip/hip_bf16.h>
#include <math.h>

#define IN_DIM 128
#define HID 256
#define OUT_DIM 40
#define EPS 1e-5f

typedef __attribute__((ext_vector_type(8))) short short8;
typedef __attribute__((ext_vector_type(4))) float floatx4;

__device__ __forceinline__ float b2f(unsigned short u) {
    union { unsigned int i; float f; } c; c.i = ((unsigned int)u) << 16; return c.f;
}
__device__ __forceinline__ unsigned short f2b(float f) {
    union { float f; unsigned int i; } c; c.f = f;
    unsigned int r = c.i + 0x7FFF + ((c.i >> 16) & 1);
    return (unsigned short)(r >> 16);
}

// ---------------- graph preprocessing ----------------

__global__ void hist_k(const int* __restrict__ dst, int* __restrict__ deg, int E) {
    for (int e = blockIdx.x * blockDim.x + threadIdx.x; e < E; e += gridDim.x * blockDim.x)
        atomicAdd(&deg[dst[e]], 1);
}

// block reduction of deg -> bsum, plus dinv = rsqrt(deg+1)
__global__ __launch_bounds__(256) void scan_a(const int* __restrict__ deg,
                                              int* __restrict__ bsum,
                                              float* __restrict__ dinv, int n) {
    __shared__ int red[256];
    int t = threadIdx.x;
    int i = blockIdx.x * 256 + t;
    int d = (i < n) ? deg[i] : 0;
    if (i < n) dinv[i] = rsqrtf((float)(d + 1));
    red[t] = d;
    __syncthreads();
    for (int off = 128; off; off >>= 1) {
        if (t < off) red[t] += red[t + off];
        __syncthreads();
    }
    if (t == 0) bsum[blockIdx.x] = red[0];
}

__global__ __launch_bounds__(256) void scan_b(const int* __restrict__ bsum,
                                              int* __restrict__ boff, int nb) {
    __shared__ int s[256];
    int t = threadIdx.x;
    s[t] = (t < nb) ? bsum[t] : 0;
    __syncthreads();
    for (int off = 1; off < 256; off <<= 1) {
        int v = 0;
        if (t >= off) v = s[t - off];
        __syncthreads();
        if (t >= off) s[t] += v;
        __syncthreads();
    }
    boff[t] = (t == 0) ? 0 : s[t - 1];   // exclusive
}

__global__ __launch_bounds__(256) void scan_c(const int* __restrict__ deg,
                                              const int* __restrict__ boff,
                                              int* __restrict__ rp, int n) {
    __shared__ int s[256];
    int t = threadIdx.x;
    int i = blockIdx.x * 256 + t;
    int d = (i < n) ? deg[i] : 0;
    s[t] = d;
    __syncthreads();
    for (int off = 1; off < 256; off <<= 1) {
        int v = 0;
        if (t >= off) v = s[t - off];
        __syncthreads();
        if (t >= off) s[t] += v;
        __syncthreads();
    }
    int base = boff[blockIdx.x];
    if (i < n) rp[i] = base + s[t] - d;
    if (i == n - 1) rp[n] = base + s[t];
}

__global__ void fill_k(const int* __restrict__ src, const int* __restrict__ dst,
                       const int* __restrict__ rp, int* __restrict__ cnt,
                       int* __restrict__ col, int E) {
    for (int e = blockIdx.x * blockDim.x + threadIdx.x; e < E; e += gridDim.x * blockDim.x) {
        int d = dst[e];
        int p = atomicAdd(&cnt[d], 1);
        col[rp[d] + p] = src[e];
    }
}

// ---------------- dtype conversion ----------------

// x (fp32) -> bf16 pre-scaled by dinv[row]; processes float4 chunks (IN_DIM=128)
__global__ void f2bs4_k(const float* __restrict__ in, const float* __restrict__ dinv,
                        unsigned short* __restrict__ out, size_t n4) {
    for (size_t i = blockIdx.x * 256 + threadIdx.x; i < n4; i += (size_t)gridDim.x * 256) {
        float4 v = ((const float4*)in)[i];
        float dv = dinv[i >> 5];       // 32 float4 per row of 128
        ushort4 o;
        o.x = f2b(v.x * dv); o.y = f2b(v.y * dv);
        o.z = f2b(v.z * dv); o.w = f2b(v.w * dv);
        ((ushort4*)out)[i] = o;
    }
}

// W1 [128][256] -> W1t [256][128] bf16 ; W2 [256][256] -> W2t [256][256] bf16
__global__ void wt12_k(const float* __restrict__ W1, const float* __restrict__ W2,
                       unsigned short* __restrict__ W1t, unsigned short* __restrict__ W2t) {
    int i = blockIdx.x * 256 + threadIdx.x;
    if (i < 256 * 128) {
        int n = i >> 7, k = i & 127;
        W1t[i] = f2b(W1[k * 256 + n]);
    } else {
        int i2 = i - 256 * 128;
        if (i2 < 256 * 256) {
            int n = i2 >> 8, k = i2 & 255;
            W2t[i2] = f2b(W2[k * 256 + n]);
        }
    }
}

// W3l = W3 @ Wl  (256x40), stored transposed+padded: W3lt[128][256] bf16.
// bias2 = b3 @ Wl + bl (fp32[40]).
__global__ void w3l_k(const float* __restrict__ W3, const float* __restrict__ Wl,
                      const float* __restrict__ b3, const float* __restrict__ bl,
                      unsigned short* __restrict__ W3lt, float* __restrict__ bias2) {
    int i = blockIdx.x * 256 + threadIdx.x;
    if (i >= 128 * 256) return;
    int n = i >> 8, k = i & 255;
    float acc = 0.f;
    if (n < OUT_DIM) {
        for (int j = 0; j < OUT_DIM; ++j)
            acc += W3[k * OUT_DIM + j] * Wl[j * OUT_DIM + n];
    }
    W3lt[i] = (n < OUT_DIM) ? f2b(acc) : 0;
    if (i < OUT_DIM) {
        float b = bl[i];
        for (int j = 0; j < OUT_DIM; ++j) b += b3[j] * Wl[j * OUT_DIM + i];
        bias2[i] = b;
    }
}

// ---------------- bf16 MFMA GEMM (optionally fused BN+ReLU on A) ----------------
// C[M][ldc](bf16) = (f(A)[M][K] @ Bt^T) * rowscale[row] + bias[col]
// BN path: f(a)[r][k] = relu(a[r][k]*scale[k]+shift[k]), scale/shift from raw stats.

template <bool BN>
__global__ __launch_bounds__(256) void gemm_bf16(const unsigned short* __restrict__ A,
                                                 const unsigned short* __restrict__ Bt,
                                                 unsigned short* __restrict__ C,
                                                 const float* __restrict__ rowscale,
                                                 const float* __restrict__ bias,
                                                 const float* __restrict__ bnstats,
                                                 const float* __restrict__ g,
                                                 const float* __restrict__ be,
                                                 float invN,
                                                 int M, int Nc, int K, int ldc) {
    __shared__ unsigned short As[128][40];  // 32 k + 8 pad
    __shared__ unsigned short Bs[128][40];
    __shared__ float s_sc[HID], s_sh[HID];
    int tid = threadIdx.x;
    if (BN) {
        float mu = bnstats[tid] * invN;
        float var = bnstats[HID + tid] * invN - mu * mu;
        float sc = g[tid] * rsqrtf(var + EPS);
        s_sc[tid] = sc;
        s_sh[tid] = be[tid] - mu * sc;
    }
    __syncthreads();

    int wave = tid >> 6, lane = tid & 63;
    int wm = wave >> 1, wn = wave & 1;
    int quad = lane >> 4, r16 = lane & 15;
    int row0 = blockIdx.y * 128, col0 = blockIdx.x * 128;

    floatx4 acc[4][4] = {};

    for (int k0 = 0; k0 < K; k0 += 32) {
#pragma unroll
        for (int i = 0; i < 2; ++i) {
            int idx = tid * 2 + i;          // 512 chunks of 8 elems
            int r = idx >> 2;               // 0..127
            int ko = (idx & 3) * 8;
            int ar = min(row0 + r, M - 1);
            union { uint4 u; unsigned short s[8]; } ra;
            ra.u = *(const uint4*)&A[(size_t)ar * K + k0 + ko];
            if (BN) {
#pragma unroll
                for (int j = 0; j < 8; ++j) {
                    int kk = k0 + ko + j;
                    float v = b2f(ra.s[j]) * s_sc[kk] + s_sh[kk];
                    ra.s[j] = f2b(fmaxf(v, 0.f));
                }
            }
            *(uint4*)&As[r][ko] = ra.u;
            *(uint4*)&Bs[r][ko] = *(const uint4*)&Bt[(size_t)(col0 + r) * K + k0 + ko];
        }
        __syncthreads();
        short8 a[4], b[4];
#pragma unroll
        for (int mt = 0; mt < 4; ++mt)
            a[mt] = *(const short8*)&As[wm * 64 + mt * 16 + r16][quad * 8];
#pragma unroll
        for (int nt = 0; nt < 4; ++nt)
            b[nt] = *(const short8*)&Bs[wn * 64 + nt * 16 + r16][quad * 8];
#pragma unroll
        for (int mt = 0; mt < 4; ++mt)
#pragma unroll
            for (int nt = 0; nt < 4; ++nt)
                acc[mt][nt] = __builtin_amdgcn_mfma_f32_16x16x32_bf16(a[mt], b[nt], acc[mt][nt], 0, 0, 0);
        __syncthreads();
    }

#pragma unroll
    for (int mt = 0; mt < 4; ++mt) {
#pragma unroll
        for (int r = 0; r < 4; ++r) {
            int row = row0 + wm * 64 + mt * 16 + quad * 4 + r;
            if (row >= M) continue;
            float dv = rowscale ? rowscale[row] : 1.f;
#pragma unroll
            for (int nt = 0; nt < 4; ++nt) {
                int colg = col0 + wn * 64 + nt * 16 + r16;
                if (colg < Nc) {
                    float v = acc[mt][nt][r] * dv + (bias ? bias[colg] : 0.f);
                    C[(size_t)row * ldc + colg] = f2b(v);
                }
            }
        }
    }
}

// ---------------- CSR gather aggregation ----------------

// 128-col (aggregate x before layer-1 GEMM). out = bf16(dv * sum)
__global__ __launch_bounds__(256) void agg_x(const unsigned short* __restrict__ m,
                                             const int* __restrict__ col,
                                             const int* __restrict__ rp,
                                             const float* __restrict__ dinv,
                                             unsigned short* __restrict__ out,
                                             int N) {
    int v = blockIdx.x * 4 + (threadIdx.x >> 6);
    if (v >= N) return;
    int lane = threadIdx.x & 63;
    int c0 = lane * 2;
    float dv = dinv[v];
    int beg = rp[v], end = rp[v + 1];
    float a0, a1;
    {
        ushort2 r = *(const ushort2*)&m[(size_t)v * IN_DIM + c0];
        a0 = b2f(r.x); a1 = b2f(r.y);
    }
    int e = beg;
    for (; e + 8 <= end; e += 8) {
        ushort2 rr[8];
#pragma unroll
        for (int j = 0; j < 8; ++j)
            rr[j] = *(const ushort2*)&m[(size_t)col[e + j] * IN_DIM + c0];
#pragma unroll
        for (int j = 0; j < 8; ++j) { a0 += b2f(rr[j].x); a1 += b2f(rr[j].y); }
    }
    for (; e < end; ++e) {
        ushort2 r = *(const ushort2*)&m[(size_t)col[e] * IN_DIM + c0];
        a0 += b2f(r.x); a1 += b2f(r.y);
    }
    ushort2 o;
    o.x = f2b(a0 * dv);
    o.y = f2b(a1 * dv);
    *(ushort2*)&out[(size_t)v * IN_DIM + c0] = o;
}

// 256-col. out[v,:] = bf16( dv * ( sum_e m'[col_e,:] + m'[v,:] ) + bias )
__global__ __launch_bounds__(256) void agg_h(const unsigned short* __restrict__ m,
                                             const int* __restrict__ col,
                                             const int* __restrict__ rp,
                                             const float* __restrict__ dinv,
                                             const float* __restrict__ bias,
                                             unsigned short* __restrict__ out,
                                             int N) {
    int v = blockIdx.x * 4 + (threadIdx.x >> 6);
    if (v >= N) return;
    int lane = threadIdx.x & 63;
    int c0 = lane * 4;
    float dv = dinv[v];
    int beg = rp[v], end = rp[v + 1];
    float a0, a1, a2, a3;
    {
        ushort4 r = *(const ushort4*)&m[(size_t)v * HID + c0];
        a0 = b2f(r.x); a1 = b2f(r.y); a2 = b2f(r.z); a3 = b2f(r.w);
    }
    int e = beg;
    for (; e + 8 <= end; e += 8) {
        ushort4 rr[8];
#pragma unroll
        for (int j = 0; j < 8; ++j)
            rr[j] = *(const ushort4*)&m[(size_t)col[e + j] * HID + c0];
#pragma unroll
        for (int j = 0; j < 8; ++j) {
            a0 += b2f(rr[j].x); a1 += b2f(rr[j].y); a2 += b2f(rr[j].z); a3 += b2f(rr[j].w);
        }
    }
    for (; e < end; ++e) {
        ushort4 r = *(const ushort4*)&m[(size_t)col[e] * HID + c0];
        a0 += b2f(r.x); a1 += b2f(r.y); a2 += b2f(r.z); a3 += b2f(r.w);
    }
    ushort4 o;
    o.x = f2b(a0 * dv + bias[c0 + 0]);
    o.y = f2b(a1 * dv + bias[c0 + 1]);
    o.z = f2b(a2 * dv + bias[c0 + 2]);
    o.w = f2b(a3 * dv + bias[c0 + 3]);
    *(ushort4*)&out[(size_t)v * HID + c0] = o;
}

// layer-3: aggregate 40-col bf16 rows, add bias2, log_softmax, write fp32 out.
__global__ __launch_bounds__(256) void agg_o_ls(const unsigned short* __restrict__ m,
                                                const int* __restrict__ col,
                                                const int* __restrict__ rp,
                                                const float* __restrict__ dinv,
                                                const float* __restrict__ bias2,
                                                float* __restrict__ out,
                                                int N) {
    int v = blockIdx.x * 4 + (threadIdx.x >> 6);
    if (v >= N) return;                       // wave-uniform
    int lane = threadIdx.x & 63;
    bool act = lane < 20;
    int c0 = lane * 2;
    float a0 = -INFINITY, a1 = -INFINITY;
    if (act) {
        float dv = dinv[v];
        int beg = rp[v], end = rp[v + 1];
        ushort2 r = *(const ushort2*)&m[(size_t)v * OUT_DIM + c0];
        a0 = b2f(r.x); a1 = b2f(r.y);
        int e = beg;
        for (; e + 8 <= end; e += 8) {
            ushort2 rr[8];
#pragma unroll
            for (int j = 0; j < 8; ++j)
                rr[j] = *(const ushort2*)&m[(size_t)col[e + j] * OUT_DIM + c0];
#pragma unroll
            for (int j = 0; j < 8; ++j) { a0 += b2f(rr[j].x); a1 += b2f(rr[j].y); }
        }
        for (; e < end; ++e) {
            ushort2 r2 = *(const ushort2*)&m[(size_t)col[e] * OUT_DIM + c0];
            a0 += b2f(r2.x); a1 += b2f(r2.y);
        }
        a0 = a0 * dv + bias2[c0 + 0];
        a1 = a1 * dv + bias2[c0 + 1];
    }
    float mx = fmaxf(a0, a1);
    for (int off = 32; off; off >>= 1) mx = fmaxf(mx, __shfl_xor(mx, off));
    float s = act ? (expf(a0 - mx) + expf(a1 - mx)) : 0.f;
    for (int off = 32; off; off >>= 1) s += __shfl_xor(s, off);
    float ls = logf(s);
    if (act) {
        out[(size_t)v * OUT_DIM + c0 + 0] = a0 - mx - ls;
        out[(size_t)v * OUT_DIM + c0 + 1] = a1 - mx - ls;
    }
}

// ---------------- BatchNorm stats (bf16 h) ----------------

__global__ __launch_bounds__(256) void bn_stats(const unsigned short* __restrict__ h,
                                                float* __restrict__ stats, int N) {
    int t = threadIdx.x;
    int r0 = blockIdx.x * 128;
    int rend = min(r0 + 128, N);
    float s = 0.f, ss = 0.f;
    for (int r = r0; r < rend; ++r) {
        float v = b2f(h[(size_t)r * HID + t]);
        s += v;
        ss += v * v;
    }
    atomicAdd(&stats[t], s);
    atomicAdd(&stats[HID + t], ss);
}

// ---------------- launch ----------------

extern "C" void kernel_launch(void* const* d_in, const int* in_sizes, int n_in,
                              void* d_out, int out_size, void* d_ws, size_t ws_size,
                              hipStream_t stream) {
    const float* x   = (const float*)d_in[0];
    const int*  eidx = (const int*)d_in[1];
    const float* W1 = (const float*)d_in[2];
    const float* b1 = (const float*)d_in[3];
    const float* g1 = (const float*)d_in[4];
    const float* be1 = (const float*)d_in[5];
    const float* W2 = (const float*)d_in[6];
    const float* b2 = (const float*)d_in[7];
    const float* g2 = (const float*)d_in[8];
    const float* be2 = (const float*)d_in[9];
    const float* W3 = (const float*)d_in[10];
    const float* b3 = (const float*)d_in[11];
    const float* Wl = (const float*)d_in[12];
    const float* bl = (const float*)d_in[13];
    float* out = (float*)d_out;

    const int N = in_sizes[0] / IN_DIM;
    const int E = in_sizes[1] / 2;
    const int* src = eidx;
    const int* dst = eidx + E;
    const int nb = (N + 255) / 256;   // scan blocks, must be <= 256

    size_t off = 0;
    char* ws = (char*)d_ws;
    auto carve = [&](size_t bytes) -> void* {
        void* p = ws + off;
        off += (bytes + 255) & ~(size_t)255;
        return p;
    };
    // contiguous zero region: degi, cnt, stats1, stats2
    size_t zbeg = off;
    int*   degi = (int*)carve((size_t)N * 4);
    int*   cnt  = (int*)carve((size_t)N * 4);
    float* stats1 = (float*)carve((size_t)2 * HID * 4);
    float* stats2 = (float*)carve((size_t)2 * HID * 4);
    size_t zlen = off - zbeg;
    float* dinv = (float*)carve((size_t)N * 4);
    int*   rp   = (int*)carve((size_t)(N + 1) * 4);
    int*   col  = (int*)carve((size_t)E * 4);
    int*   bsum = (int*)carve(256 * 4);
    int*   boff = (int*)carve(257 * 4);
    unsigned short* xb   = (unsigned short*)carve((size_t)N * IN_DIM * 2);
    unsigned short* axb  = (unsigned short*)carve((size_t)N * IN_DIM * 2);
    unsigned short* W1t  = (unsigned short*)carve((size_t)256 * IN_DIM * 2);
    unsigned short* W2t  = (unsigned short*)carve((size_t)256 * HID * 2);
    unsigned short* W3lt = (unsigned short*)carve((size_t)128 * HID * 2);
    float* bias2 = (float*)carve((size_t)OUT_DIM * 4);
    unsigned short* mbuf = (unsigned short*)carve((size_t)N * HID * 2);
    unsigned short* hbuf = (unsigned short*)carve((size_t)N * HID * 2);

    // --- zero + graph preprocessing ---
    hipMemsetAsync(ws + zbeg, 0, zlen, stream);
    hist_k<<<1024, 256, 0, stream>>>(dst, degi, E);
    scan_a<<<nb, 256, 0, stream>>>(degi, bsum, dinv, N);
    scan_b<<<1, 256, 0, stream>>>(bsum, boff, nb);
    scan_c<<<nb, 256, 0, stream>>>(degi, boff, rp, N);
    fill_k<<<1024, 256, 0, stream>>>(src, dst, rp, cnt, col, E);

    // --- weight/dtype prep ---
    f2bs4_k<<<1024, 256, 0, stream>>>(x, dinv, xb, (size_t)N * IN_DIM / 4);
    wt12_k<<<(256 * 128 + 256 * 256 + 255) / 256, 256, 0, stream>>>(W1, W2, W1t, W2t);
    w3l_k<<<128, 256, 0, stream>>>(W3, Wl, b3, bl, W3lt, bias2);

    int mblocks = (N + 127) / 128;
    dim3 gg1(2, mblocks), gg3(1, mblocks);
    int aggblocks = (N + 3) / 4;
    float invN = 1.f / (float)N;

    // --- layer 1: aggregate x, GEMM (+b1) ---
    agg_x<<<aggblocks, 256, 0, stream>>>(xb, col, rp, dinv, axb, N);
    gemm_bf16<false><<<gg1, 256, 0, stream>>>(axb, W1t, hbuf, nullptr, b1,
                                              nullptr, nullptr, nullptr, invN,
                                              N, HID, IN_DIM, HID);
    bn_stats<<<(N + 127) / 128, 256, 0, stream>>>(hbuf, stats1, N);

    // --- layer 2: GEMM (BN1+ReLU on A, xdinv epilogue), aggregate (+b2) ---
    gemm_bf16<true><<<gg1, 256, 0, stream>>>(hbuf, W2t, mbuf, dinv, nullptr,
                                             stats1, g1, be1, invN,
                                             N, HID, HID, HID);
    agg_h<<<aggblocks, 256, 0, stream>>>(mbuf, col, rp, dinv, b2, hbuf, N);
    bn_stats<<<(N + 127) / 128, 256, 0, stream>>>(hbuf, stats2, N);

    // --- layer 3 + head: GEMM with W3*Wl (BN2+ReLU on A), aggregate + log_softmax ---
    gemm_bf16<true><<<gg3, 256, 0, stream>>>(hbuf, W3lt, mbuf, dinv, nullptr,
                                             stats2, g2, be2, invN,
                                             N, OUT_DIM, HID, OUT_DIM);
    agg_o_ls<<<aggblocks, 256, 0, stream>>>(mbuf, col, rp, dinv, bias2, out, N);
}

// Round 5
// 490.547 us; speedup vs baseline: 2.0941x; 1.0129x over previous
//
#include <hip/hip_runtime.h>
#include <hip/hip_bf16.h>
#include <math.h>

#define IN_DIM 128
#define HID 256
#define OUT_DIM 40
#define OUT_PAD 64
#define EPS 1e-5f

typedef __attribute__((ext_vector_type(8))) short short8;
typedef __attribute__((ext_vector_type(4))) float floatx4;

__device__ __forceinline__ float b2f(unsigned short u) {
    union { unsigned int i; float f; } c; c.i = ((unsigned int)u) << 16; return c.f;
}
__device__ __forceinline__ unsigned short f2b(float f) {
    union { float f; unsigned int i; } c; c.f = f;
    unsigned int r = c.i + 0x7FFF + ((c.i >> 16) & 1);
    return (unsigned short)(r >> 16);
}

union U8 { uint4 u; unsigned short s[8]; };

// ---------------- graph preprocessing ----------------

__global__ void hist_k(const int* __restrict__ dst, int* __restrict__ deg, int E) {
    for (int e = blockIdx.x * blockDim.x + threadIdx.x; e < E; e += gridDim.x * blockDim.x)
        atomicAdd(&deg[dst[e]], 1);
}

// block reduction of deg -> bsum, plus dinv = rsqrt(deg+1)
__global__ __launch_bounds__(256) void scan_a(const int* __restrict__ deg,
                                              int* __restrict__ bsum,
                                              float* __restrict__ dinv, int n) {
    __shared__ int red[256];
    int t = threadIdx.x;
    int i = blockIdx.x * 256 + t;
    int d = (i < n) ? deg[i] : 0;
    if (i < n) dinv[i] = rsqrtf((float)(d + 1));
    red[t] = d;
    __syncthreads();
    for (int off = 128; off; off >>= 1) {
        if (t < off) red[t] += red[t + off];
        __syncthreads();
    }
    if (t == 0) bsum[blockIdx.x] = red[0];
}

__global__ __launch_bounds__(256) void scan_b(const int* __restrict__ bsum,
                                              int* __restrict__ boff, int nb) {
    __shared__ int s[256];
    int t = threadIdx.x;
    s[t] = (t < nb) ? bsum[t] : 0;
    __syncthreads();
    for (int off = 1; off < 256; off <<= 1) {
        int v = 0;
        if (t >= off) v = s[t - off];
        __syncthreads();
        if (t >= off) s[t] += v;
        __syncthreads();
    }
    boff[t] = (t == 0) ? 0 : s[t - 1];   // exclusive
}

__global__ __launch_bounds__(256) void scan_c(const int* __restrict__ deg,
                                              const int* __restrict__ boff,
                                              int* __restrict__ rp, int n) {
    __shared__ int s[256];
    int t = threadIdx.x;
    int i = blockIdx.x * 256 + t;
    int d = (i < n) ? deg[i] : 0;
    s[t] = d;
    __syncthreads();
    for (int off = 1; off < 256; off <<= 1) {
        int v = 0;
        if (t >= off) v = s[t - off];
        __syncthreads();
        if (t >= off) s[t] += v;
        __syncthreads();
    }
    int base = boff[blockIdx.x];
    if (i < n) rp[i] = base + s[t] - d;
    if (i == n - 1) rp[n] = base + s[t];
}

__global__ void fill_k(const int* __restrict__ src, const int* __restrict__ dst,
                       const int* __restrict__ rp, int* __restrict__ cnt,
                       int* __restrict__ col, int E) {
    for (int e = blockIdx.x * blockDim.x + threadIdx.x; e < E; e += gridDim.x * blockDim.x) {
        int d = dst[e];
        int p = atomicAdd(&cnt[d], 1);
        col[rp[d] + p] = src[e];
    }
}

// ---------------- dtype / weight prep ----------------

// x (fp32) -> bf16 pre-scaled by dinv[row]; float4 chunks (IN_DIM=128)
__global__ void f2bs4_k(const float* __restrict__ in, const float* __restrict__ dinv,
                        unsigned short* __restrict__ out, size_t n4) {
    for (size_t i = blockIdx.x * 256 + threadIdx.x; i < n4; i += (size_t)gridDim.x * 256) {
        float4 v = ((const float4*)in)[i];
        float dv = dinv[i >> 5];       // 32 float4 per row of 128
        ushort4 o;
        o.x = f2b(v.x * dv); o.y = f2b(v.y * dv);
        o.z = f2b(v.z * dv); o.w = f2b(v.w * dv);
        ((ushort4*)out)[i] = o;
    }
}

// One dispatch: W1t[256][128], W2t[256][256], W3lt[128][256] = (W3@Wl)^T padded,
// bias2[40] = b3@Wl + bl.
__global__ void wt_all_k(const float* __restrict__ W1, const float* __restrict__ W2,
                         const float* __restrict__ W3, const float* __restrict__ Wl,
                         const float* __restrict__ b3, const float* __restrict__ bl,
                         unsigned short* __restrict__ W1t, unsigned short* __restrict__ W2t,
                         unsigned short* __restrict__ W3lt, float* __restrict__ bias2) {
    int i = blockIdx.x * 256 + threadIdx.x;
    const int n1 = 256 * 128, n2 = 256 * 256, n3 = 128 * 256;
    if (i < n1) {
        int n = i >> 7, k = i & 127;
        W1t[i] = f2b(W1[k * 256 + n]);
    } else if (i < n1 + n2) {
        int i2 = i - n1;
        int n = i2 >> 8, k = i2 & 255;
        W2t[i2] = f2b(W2[k * 256 + n]);
    } else if (i < n1 + n2 + n3) {
        int i3 = i - n1 - n2;
        int n = i3 >> 8, k = i3 & 255;
        float acc = 0.f;
        if (n < OUT_DIM) {
            for (int j = 0; j < OUT_DIM; ++j)
                acc += W3[k * OUT_DIM + j] * Wl[j * OUT_DIM + n];
        }
        W3lt[i3] = (n < OUT_DIM) ? f2b(acc) : 0;
        if (i3 < OUT_DIM) {
            float b = bl[i3];
            for (int j = 0; j < OUT_DIM; ++j) b += b3[j] * Wl[j * OUT_DIM + i3];
            bias2[i3] = b;
        }
    }
}

// ---------------- bf16 MFMA GEMM (optionally fused BN+ReLU on A) ----------------

template <bool BN>
__global__ __launch_bounds__(256) void gemm_bf16(const unsigned short* __restrict__ A,
                                                 const unsigned short* __restrict__ Bt,
                                                 unsigned short* __restrict__ C,
                                                 const float* __restrict__ rowscale,
                                                 const float* __restrict__ bias,
                                                 const float* __restrict__ bnstats,
                                                 const float* __restrict__ g,
                                                 const float* __restrict__ be,
                                                 float invN,
                                                 int M, int Nc, int K, int ldc) {
    __shared__ unsigned short As[128][40];  // 32 k + 8 pad
    __shared__ unsigned short Bs[128][40];
    __shared__ float s_sc[HID], s_sh[HID];
    int tid = threadIdx.x;
    if (BN) {
        float mu = bnstats[tid] * invN;
        float var = bnstats[HID + tid] * invN - mu * mu;
        float sc = g[tid] * rsqrtf(var + EPS);
        s_sc[tid] = sc;
        s_sh[tid] = be[tid] - mu * sc;
    }
    __syncthreads();

    int wave = tid >> 6, lane = tid & 63;
    int wm = wave >> 1, wn = wave & 1;
    int quad = lane >> 4, r16 = lane & 15;
    int row0 = blockIdx.y * 128, col0 = blockIdx.x * 128;

    floatx4 acc[4][4] = {};

    for (int k0 = 0; k0 < K; k0 += 32) {
#pragma unroll
        for (int i = 0; i < 2; ++i) {
            int idx = tid * 2 + i;
            int r = idx >> 2;
            int ko = (idx & 3) * 8;
            int ar = min(row0 + r, M - 1);
            U8 ra;
            ra.u = *(const uint4*)&A[(size_t)ar * K + k0 + ko];
            if (BN) {
#pragma unroll
                for (int j = 0; j < 8; ++j) {
                    int kk = k0 + ko + j;
                    float v = b2f(ra.s[j]) * s_sc[kk] + s_sh[kk];
                    ra.s[j] = f2b(fmaxf(v, 0.f));
                }
            }
            *(uint4*)&As[r][ko] = ra.u;
            *(uint4*)&Bs[r][ko] = *(const uint4*)&Bt[(size_t)(col0 + r) * K + k0 + ko];
        }
        __syncthreads();
        short8 a[4], b[4];
#pragma unroll
        for (int mt = 0; mt < 4; ++mt)
            a[mt] = *(const short8*)&As[wm * 64 + mt * 16 + r16][quad * 8];
#pragma unroll
        for (int nt = 0; nt < 4; ++nt)
            b[nt] = *(const short8*)&Bs[wn * 64 + nt * 16 + r16][quad * 8];
#pragma unroll
        for (int mt = 0; mt < 4; ++mt)
#pragma unroll
            for (int nt = 0; nt < 4; ++nt)
                acc[mt][nt] = __builtin_amdgcn_mfma_f32_16x16x32_bf16(a[mt], b[nt], acc[mt][nt], 0, 0, 0);
        __syncthreads();
    }

#pragma unroll
    for (int mt = 0; mt < 4; ++mt) {
#pragma unroll
        for (int r = 0; r < 4; ++r) {
            int row = row0 + wm * 64 + mt * 16 + quad * 4 + r;
            if (row >= M) continue;
            float dv = rowscale ? rowscale[row] : 1.f;
#pragma unroll
            for (int nt = 0; nt < 4; ++nt) {
                int colg = col0 + wn * 64 + nt * 16 + r16;
                if (colg < Nc) {
                    float v = acc[mt][nt][r] * dv + (bias ? bias[colg] : 0.f);
                    C[(size_t)row * ldc + colg] = f2b(v);
                }
            }
        }
    }
}

// ---------------- CSR gather aggregation (split-wave, 16 B/lane) ----------------

// 256-col: 32 lanes x 16 B per row, 2 edges per wave-load.
__global__ __launch_bounds__(256) void agg_h(const unsigned short* __restrict__ m,
                                             const int* __restrict__ col,
                                             const int* __restrict__ rp,
                                             const float* __restrict__ dinv,
                                             const float* __restrict__ bias,
                                             unsigned short* __restrict__ out,
                                             int N) {
    int v = blockIdx.x * 4 + (threadIdx.x >> 6);
    if (v >= N) return;
    int lane = threadIdx.x & 63;
    int half = lane >> 5;
    int c0 = (lane & 31) * 8;          // 8 cols = 16 B
    float dv = dinv[v];
    int beg = rp[v], end = rp[v + 1];
    float a[8] = {};
    if (half == 0) {
        U8 r; r.u = *(const uint4*)&m[(size_t)v * HID + c0];
#pragma unroll
        for (int k = 0; k < 8; ++k) a[k] = b2f(r.s[k]);
    }
    int e = beg;
    for (; e + 8 <= end; e += 8) {
        int idx[4];
#pragma unroll
        for (int j = 0; j < 4; ++j) idx[j] = col[e + 2 * j + half];
        U8 rr[4];
#pragma unroll
        for (int j = 0; j < 4; ++j)
            rr[j].u = *(const uint4*)&m[(size_t)idx[j] * HID + c0];
#pragma unroll
        for (int j = 0; j < 4; ++j)
#pragma unroll
            for (int k = 0; k < 8; ++k) a[k] += b2f(rr[j].s[k]);
    }
    for (; e < end; e += 2) {
        int t = e + half;
        if (t < end) {
            U8 r; r.u = *(const uint4*)&m[(size_t)col[t] * HID + c0];
#pragma unroll
            for (int k = 0; k < 8; ++k) a[k] += b2f(r.s[k]);
        }
    }
#pragma unroll
    for (int k = 0; k < 8; ++k) a[k] += __shfl_xor(a[k], 32);
    if (half == 0) {
        U8 o;
#pragma unroll
        for (int k = 0; k < 8; ++k) o.s[k] = f2b(a[k] * dv + bias[c0 + k]);
        *(uint4*)&out[(size_t)v * HID + c0] = o.u;
    }
}

// 128-col: 16 lanes x 16 B per row, 4 edges per wave-load. out = bf16(dv*sum)
__global__ __launch_bounds__(256) void agg_x(const unsigned short* __restrict__ m,
                                             const int* __restrict__ col,
                                             const int* __restrict__ rp,
                                             const float* __restrict__ dinv,
                                             unsigned short* __restrict__ out,
                                             int N) {
    int v = blockIdx.x * 4 + (threadIdx.x >> 6);
    if (v >= N) return;
    int lane = threadIdx.x & 63;
    int q = lane >> 4;
    int c0 = (lane & 15) * 8;
    float dv = dinv[v];
    int beg = rp[v], end = rp[v + 1];
    float a[8] = {};
    if (q == 0) {
        U8 r; r.u = *(const uint4*)&m[(size_t)v * IN_DIM + c0];
#pragma unroll
        for (int k = 0; k < 8; ++k) a[k] = b2f(r.s[k]);
    }
    int e = beg;
    for (; e + 8 <= end; e += 8) {
        int idx[2];
#pragma unroll
        for (int j = 0; j < 2; ++j) idx[j] = col[e + 4 * j + q];
        U8 rr[2];
#pragma unroll
        for (int j = 0; j < 2; ++j)
            rr[j].u = *(const uint4*)&m[(size_t)idx[j] * IN_DIM + c0];
#pragma unroll
        for (int j = 0; j < 2; ++j)
#pragma unroll
            for (int k = 0; k < 8; ++k) a[k] += b2f(rr[j].s[k]);
    }
    for (; e < end; e += 4) {
        int t = e + q;
        if (t < end) {
            U8 r; r.u = *(const uint4*)&m[(size_t)col[t] * IN_DIM + c0];
#pragma unroll
            for (int k = 0; k < 8; ++k) a[k] += b2f(r.s[k]);
        }
    }
#pragma unroll
    for (int k = 0; k < 8; ++k) {
        a[k] += __shfl_xor(a[k], 16);
        a[k] += __shfl_xor(a[k], 32);
    }
    if (q == 0) {
        U8 o;
#pragma unroll
        for (int k = 0; k < 8; ++k) o.s[k] = f2b(a[k] * dv);
        *(uint4*)&out[(size_t)v * IN_DIM + c0] = o.u;
    }
}

// layer-3 + log_softmax: m3 is [N][64] bf16 (cols 40-63 zero). 8 lanes x 16 B
// per row, 8 edges per wave-load. fp32 out [N][40].
__global__ __launch_bounds__(256) void agg_o_ls(const unsigned short* __restrict__ m,
                                                const int* __restrict__ col,
                                                const int* __restrict__ rp,
                                                const float* __restrict__ dinv,
                                                const float* __restrict__ bias2,
                                                float* __restrict__ out,
                                                int N) {
    int v = blockIdx.x * 4 + (threadIdx.x >> 6);
    if (v >= N) return;
    int lane = threadIdx.x & 63;
    int slot = lane >> 3;
    int li = lane & 7;
    int c0 = li * 8;                   // cols within padded 64
    float dv = dinv[v];
    int beg = rp[v], end = rp[v + 1];
    float a[8] = {};
    if (slot == 0) {
        U8 r; r.u = *(const uint4*)&m[(size_t)v * OUT_PAD + c0];
#pragma unroll
        for (int k = 0; k < 8; ++k) a[k] = b2f(r.s[k]);
    }
    int e = beg;
    for (; e + 16 <= end; e += 16) {
        int idx[2];
        idx[0] = col[e + slot];
        idx[1] = col[e + 8 + slot];
        U8 rr[2];
#pragma unroll
        for (int j = 0; j < 2; ++j)
            rr[j].u = *(const uint4*)&m[(size_t)idx[j] * OUT_PAD + c0];
#pragma unroll
        for (int j = 0; j < 2; ++j)
#pragma unroll
            for (int k = 0; k < 8; ++k) a[k] += b2f(rr[j].s[k]);
    }
    for (; e < end; e += 8) {
        int t = e + slot;
        if (t < end) {
            U8 r; r.u = *(const uint4*)&m[(size_t)col[t] * OUT_PAD + c0];
#pragma unroll
            for (int k = 0; k < 8; ++k) a[k] += b2f(r.s[k]);
        }
    }
#pragma unroll
    for (int k = 0; k < 8; ++k) {
        a[k] += __shfl_xor(a[k], 8);
        a[k] += __shfl_xor(a[k], 16);
        a[k] += __shfl_xor(a[k], 32);
    }
    // now every lane holds the column sums for its li (cols c0..c0+7)
    bool valid = (li < 5);             // cols < 40
    float mx = -INFINITY;
#pragma unroll
    for (int k = 0; k < 8; ++k) {
        float val = valid ? (a[k] * dv + bias2[c0 + k]) : -INFINITY;
        a[k] = val;
        mx = fmaxf(mx, val);
    }
    mx = fmaxf(mx, __shfl_xor(mx, 1));
    mx = fmaxf(mx, __shfl_xor(mx, 2));
    mx = fmaxf(mx, __shfl_xor(mx, 4));
    float s = 0.f;
    if (valid) {
#pragma unroll
        for (int k = 0; k < 8; ++k) s += expf(a[k] - mx);
    }
    s += __shfl_xor(s, 1);
    s += __shfl_xor(s, 2);
    s += __shfl_xor(s, 4);
    float ls = mx + logf(s);
    if (slot == 0 && valid) {
        float4 o0, o1;
        o0.x = a[0] - ls; o0.y = a[1] - ls; o0.z = a[2] - ls; o0.w = a[3] - ls;
        o1.x = a[4] - ls; o1.y = a[5] - ls; o1.z = a[6] - ls; o1.w = a[7] - ls;
        float* p = &out[(size_t)v * OUT_DIM + c0];
        *(float4*)p = o0;
        *(float4*)(p + 4) = o1;
    }
}

// ---------------- BatchNorm stats (bf16 h) ----------------

__global__ __launch_bounds__(256) void bn_stats(const unsigned short* __restrict__ h,
                                                float* __restrict__ stats, int N) {
    int t = threadIdx.x;
    int r0 = blockIdx.x * 128;
    int rend = min(r0 + 128, N);
    float s = 0.f, ss = 0.f;
    for (int r = r0; r < rend; ++r) {
        float v = b2f(h[(size_t)r * HID + t]);
        s += v;
        ss += v * v;
    }
    atomicAdd(&stats[t], s);
    atomicAdd(&stats[HID + t], ss);
}

// ---------------- launch ----------------

extern "C" void kernel_launch(void* const* d_in, const int* in_sizes, int n_in,
                              void* d_out, int out_size, void* d_ws, size_t ws_size,
                              hipStream_t stream) {
    const float* x   = (const float*)d_in[0];
    const int*  eidx = (const int*)d_in[1];
    const float* W1 = (const float*)d_in[2];
    const float* b1 = (const float*)d_in[3];
    const float* g1 = (const float*)d_in[4];
    const float* be1 = (const float*)d_in[5];
    const float* W2 = (const float*)d_in[6];
    const float* b2 = (const float*)d_in[7];
    const float* g2 = (const float*)d_in[8];
    const float* be2 = (const float*)d_in[9];
    const float* W3 = (const float*)d_in[10];
    const float* b3 = (const float*)d_in[11];
    const float* Wl = (const float*)d_in[12];
    const float* bl = (const float*)d_in[13];
    float* out = (float*)d_out;

    const int N = in_sizes[0] / IN_DIM;
    const int E = in_sizes[1] / 2;
    const int* src = eidx;
    const int* dst = eidx + E;
    const int nb = (N + 255) / 256;   // scan blocks, must be <= 256

    size_t off = 0;
    char* ws = (char*)d_ws;
    auto carve = [&](size_t bytes) -> void* {
        void* p = ws + off;
        off += (bytes + 255) & ~(size_t)255;
        return p;
    };
    // contiguous zero region: degi, cnt, stats1, stats2
    size_t zbeg = off;
    int*   degi = (int*)carve((size_t)N * 4);
    int*   cnt  = (int*)carve((size_t)N * 4);
    float* stats1 = (float*)carve((size_t)2 * HID * 4);
    float* stats2 = (float*)carve((size_t)2 * HID * 4);
    size_t zlen = off - zbeg;
    float* dinv = (float*)carve((size_t)N * 4);
    int*   rp   = (int*)carve((size_t)(N + 1) * 4);
    int*   col  = (int*)carve((size_t)E * 4);
    int*   bsum = (int*)carve(256 * 4);
    int*   boff = (int*)carve(257 * 4);
    unsigned short* xb   = (unsigned short*)carve((size_t)N * IN_DIM * 2);
    unsigned short* axb  = (unsigned short*)carve((size_t)N * IN_DIM * 2);
    unsigned short* W1t  = (unsigned short*)carve((size_t)256 * IN_DIM * 2);
    unsigned short* W2t  = (unsigned short*)carve((size_t)256 * HID * 2);
    unsigned short* W3lt = (unsigned short*)carve((size_t)128 * HID * 2);
    float* bias2 = (float*)carve((size_t)OUT_DIM * 4);
    unsigned short* mbuf = (unsigned short*)carve((size_t)N * HID * 2);
    unsigned short* hbuf = (unsigned short*)carve((size_t)N * HID * 2);

    // --- zero + graph preprocessing ---
    hipMemsetAsync(ws + zbeg, 0, zlen, stream);
    hist_k<<<1024, 256, 0, stream>>>(dst, degi, E);
    scan_a<<<nb, 256, 0, stream>>>(degi, bsum, dinv, N);
    scan_b<<<1, 256, 0, stream>>>(bsum, boff, nb);
    scan_c<<<nb, 256, 0, stream>>>(degi, boff, rp, N);
    fill_k<<<1024, 256, 0, stream>>>(src, dst, rp, cnt, col, E);

    // --- weight/dtype prep ---
    f2bs4_k<<<1024, 256, 0, stream>>>(x, dinv, xb, (size_t)N * IN_DIM / 4);
    wt_all_k<<<(256 * 128 + 256 * 256 + 128 * 256 + 255) / 256, 256, 0, stream>>>(
        W1, W2, W3, Wl, b3, bl, W1t, W2t, W3lt, bias2);

    int mblocks = (N + 127) / 128;
    dim3 gg1(2, mblocks), gg3(1, mblocks);
    int aggblocks = (N + 3) / 4;
    float invN = 1.f / (float)N;

    // --- layer 1: aggregate x, GEMM (+b1) ---
    agg_x<<<aggblocks, 256, 0, stream>>>(xb, col, rp, dinv, axb, N);
    gemm_bf16<false><<<gg1, 256, 0, stream>>>(axb, W1t, hbuf, nullptr, b1,
                                              nullptr, nullptr, nullptr, invN,
                                              N, HID, IN_DIM, HID);
    bn_stats<<<(N + 127) / 128, 256, 0, stream>>>(hbuf, stats1, N);

    // --- layer 2: GEMM (BN1+ReLU on A, xdinv epilogue), aggregate (+b2) ---
    gemm_bf16<true><<<gg1, 256, 0, stream>>>(hbuf, W2t, mbuf, dinv, nullptr,
                                             stats1, g1, be1, invN,
                                             N, HID, HID, HID);
    agg_h<<<aggblocks, 256, 0, stream>>>(mbuf, col, rp, dinv, b2, hbuf, N);
    bn_stats<<<(N + 127) / 128, 256, 0, stream>>>(hbuf, stats2, N);

    // --- layer 3 + head: GEMM with W3*Wl (BN2+ReLU on A), 64-col padded out ---
    gemm_bf16<true><<<gg3, 256, 0, stream>>>(hbuf, W3lt, mbuf, dinv, nullptr,
                                             stats2, g2, be2, invN,
                                             N, OUT_PAD, HID, OUT_PAD);
    agg_o_ls<<<aggblocks, 256, 0, stream>>>(mbuf, col, rp, dinv, bias2, out, N);
}